// Round 1
// 357.353 us; speedup vs baseline: 1.0213x; 1.0213x over previous
//
#include <hip/hip_runtime.h>

typedef unsigned int u32;
typedef __bf16 bf16x8 __attribute__((ext_vector_type(8)));
typedef __bf16 bf16x4v __attribute__((ext_vector_type(4)));
typedef _Float16 f16x8 __attribute__((ext_vector_type(8)));
typedef float f32x4 __attribute__((ext_vector_type(4)));

#define Tn 4
#define Bn 32
#define Cn 384
#define Nn 196
#define Hn 12
#define CNn (Cn*Nn)         // 75264
#define BCNn (Bn*CNn)       // 2408448
#define BHNn (Bn*Hn*Nn)     // 75264
#define PBITS (Tn*BHNn)     // 301056
#define TBCNn (Tn*BCNn)     // 9633792
#define NCOLS 6272          // B*N
#define WSZ 147456          // 384*384

// fp32 -> 3-way bf16 split (residual ~2^-24 rel)
__device__ __forceinline__ void split3(float v, __bf16& h, __bf16& m, __bf16& l) {
  h = (__bf16)v;  float r = v - (float)h;
  m = (__bf16)r;  float r2 = r - (float)m;
  l = (__bf16)r2;
}
// fp32 -> 2-way f16 split (residual ~2^-22 rel)
__device__ __forceinline__ void split2h(float v, _Float16& h, _Float16& l) {
  h = (_Float16)v;  l = (_Float16)(v - (float)h);
}

// direct global->LDS 16B copy: lane i lands at ldsbase + i*16 (wave-uniform base)
__device__ __forceinline__ void gl_lds16(const void* g, void* l) {
  __builtin_amdgcn_global_load_lds(
      (const __attribute__((address_space(1))) unsigned int*)g,
      (__attribute__((address_space(3))) unsigned int*)l, 16, 0, 0);
}

// ---------------------------------------------------------------------------
// W split: QKV (p<3) -> iv-scaled f16 2-split; proj -> iv-scaled bf16 3-split.
// ---------------------------------------------------------------------------
struct WSplitArgs {
  const float* w[4]; const float* g[4]; const float* be[4];
  const float* mu[4]; const float* va[4]; const float* bias;
};
__global__ __launch_bounds__(256) void split_w(
    WSplitArgs a, _Float16* __restrict__ wsp16, __bf16* __restrict__ wspb,
    float* __restrict__ shv) {
  const int i = blockIdx.x * 256 + threadIdx.x;   // < 589824
  const int p = i / WSZ, r = i - p * WSZ;
  const int o = r / Cn;
  const float iv = a.g[p][o] / sqrtf(a.va[p][o] + 1e-5f);
  const float wv = a.w[p][r] * iv;
  if (p < 3) {
    _Float16 h, l;
    split2h(wv, h, l);
    wsp16[(size_t)(p * 2 + 0) * WSZ + r] = h;
    wsp16[(size_t)(p * 2 + 1) * WSZ + r] = l;
  } else {
    __bf16 h, m, l;
    split3(wv, h, m, l);
    wspb[(size_t)0 * WSZ + r] = h;
    wspb[(size_t)1 * WSZ + r] = m;
    wspb[(size_t)2 * WSZ + r] = l;
  }
  if (r - o * Cn == 0) {
    float sh = a.be[p][o] - a.mu[p][o] * iv;
    if (p == 3) sh += a.bias[o] * iv;
    shv[p * Cn + o] = sh;
  }
}

// ---------------------------------------------------------------------------
// x [t,b,c,n] -> pre-split f16 planes xs[s][t][col=(b,n)][c], s=h/l.
// Split done ONCE here instead of per-(p,mt)-block in the GEMM (9x redundant).
// Grid (4,32,12): z = ct*4 + n-chunk -> 1536 blocks.
// ---------------------------------------------------------------------------
__global__ __launch_bounds__(256) void transpose_split_x(
    const float* __restrict__ x, _Float16* __restrict__ xs) {
  __shared__ float tile[49 * 130];
  const int t = blockIdx.x, b = blockIdx.y;
  const int ct = blockIdx.z >> 2, nch = blockIdx.z & 3;
  const int c0 = ct * 128, n0 = nch * 49;
  const int tid = threadIdx.x;
  for (int idx = tid; idx < 49 * 128; idx += 256) {
    const int n = idx % 49, c = idx / 49;
    tile[n * 130 + c] = x[(size_t)t * BCNn + (size_t)b * CNn +
                          (size_t)(c0 + c) * Nn + n0 + n];
  }
  __syncthreads();
  for (int idx = tid; idx < 49 * 64; idx += 256) {
    const int cp = idx & 63, n = idx >> 6;
    const float v0 = tile[n * 130 + cp * 2];
    const float v1 = tile[n * 130 + cp * 2 + 1];
    _Float16 h0, l0, h1, l1;
    split2h(v0, h0, l0);
    split2h(v1, h1, l1);
    const size_t col = (size_t)t * NCOLS + (size_t)b * Nn + n0 + n;
    union { _Float16 f[2]; u32 u; } uh, ul;
    uh.f[0] = h0; uh.f[1] = h1;
    ul.f[0] = l0; ul.f[1] = l1;
    ((u32*)(xs + col * Cn + c0))[cp] = uh.u;
    ((u32*)(xs + (size_t)TBCNn + col * Cn + c0))[cp] = ul.u;
  }
}

// ---------------------------------------------------------------------------
// QKV GEMM, 3-product f16 2-split MFMA. Staging via global_load_lds dwordx4
// (m97 pattern): linear LDS dest, per-lane pre-swizzled SOURCE address so the
// XOR-swizzled fragment reads (bank-conflict-free) see the same layout as the
// previous reg-staged version -> bit-identical MFMA inputs. Grid 1800,
// XCD-swizzled.
// ---------------------------------------------------------------------------
__global__ __launch_bounds__(256, 3) void gemm_qkv_f16(
    const _Float16* __restrict__ xs,    // [2][t][col][c] f16 pre-split
    const _Float16* __restrict__ wsp16, // [3][2][o][c] iv-scaled f16 2-split
    const float* __restrict__ shv,      // [4][o]
    float* __restrict__ yT)             // 3 contiguous [t][col][o]
{
  __shared__ _Float16 Asw[2][128][32];
  __shared__ _Float16 Bsw[2][128][32];
  const int bid = blockIdx.x;
  const int xcd = bid & 7, slot = bid >> 3;      // slot 0..224
  const int gl = slot / 9, v = slot - gl * 9;
  const int group = xcd * 25 + gl;               // 0..199
  if (group >= 196) return;
  const int colt = group % 49, t = group / 49;
  const int col0 = colt * 128;
  const int p = v / 3, mt = v - p * 3;
  const int o0 = mt * 128;
  const int tid = threadIdx.x, lane = tid & 63, wid = tid >> 6;
  const int wm = wid >> 1, wn = wid & 1;
  const int quad = lane >> 4, nl = lane & 15;

  // per-lane staging source addresses. chunk c = i*256 + wid*64 + lane maps to
  // LDS byte c*16 == [s=c>>9][row=(c>>2)&127][kb=c&3]; source chunk index is
  // kb ^ ((row>>1)&3) so that LDS[s][row][kbp] = global(row, kbp^f(row)),
  // matching the fragment-read swizzle ka = (quad ^ ((row>>1)&3))*8.
  const char* aSrc[4];
  const char* bSrc[4];
#pragma unroll
  for (int i = 0; i < 4; ++i) {
    const int c = i * 256 + wid * 64 + lane;
    const int s = c >> 9, row = (c >> 2) & 127, kb = c & 3;
    const int kbs = kb ^ ((row >> 1) & 3);
    aSrc[i] = (const char*)(wsp16 + (size_t)(p * 2 + s) * WSZ +
                            (size_t)(o0 + row) * Cn + kbs * 8);
    bSrc[i] = (const char*)(xs + (size_t)s * TBCNn +
                            ((size_t)t * NCOLS + col0 + row) * (size_t)Cn +
                            kbs * 8);
  }
  char* aDst = (char*)&Asw[0][0][0] + wid * 1024;
  char* bDst = (char*)&Bsw[0][0][0] + wid * 1024;

  f32x4 acc[4][4] = {};

  for (int kk = 0; kk < 12; ++kk) {
    const int koff = kk * 64;   // 32 f16 = 64 bytes per K-step
#pragma unroll
    for (int i = 0; i < 4; ++i) {
      gl_lds16(aSrc[i] + koff, aDst + i * 4096);
      gl_lds16(bSrc[i] + koff, bDst + i * 4096);
    }
    __syncthreads();
    f16x8 af[2][4], bfr[2][4];
#pragma unroll
    for (int i = 0; i < 4; ++i) {
      const int ra = wm * 64 + i * 16 + nl;
      const int rb = wn * 64 + i * 16 + nl;
      const int ka = (quad ^ ((ra >> 1) & 3)) * 8;
      const int kb2 = (quad ^ ((rb >> 1) & 3)) * 8;
#pragma unroll
      for (int s = 0; s < 2; ++s) {
        af[s][i]  = *(const f16x8*)&Asw[s][ra][ka];
        bfr[s][i] = *(const f16x8*)&Bsw[s][rb][kb2];
      }
    }
#pragma unroll
    for (int mi = 0; mi < 4; ++mi)
#pragma unroll
      for (int ni = 0; ni < 4; ++ni) {
        f32x4 c = acc[mi][ni];
        c = __builtin_amdgcn_mfma_f32_16x16x32_f16(af[0][mi], bfr[0][ni], c, 0, 0, 0);
        c = __builtin_amdgcn_mfma_f32_16x16x32_f16(af[0][mi], bfr[1][ni], c, 0, 0, 0);
        c = __builtin_amdgcn_mfma_f32_16x16x32_f16(af[1][mi], bfr[0][ni], c, 0, 0, 0);
        acc[mi][ni] = c;
      }
    __syncthreads();
  }
  float* yTp = yT + (size_t)p * TBCNn;
#pragma unroll
  for (int mi = 0; mi < 4; ++mi) {
    const int ob = o0 + wm * 64 + mi * 16 + quad * 4;
    const f32x4 sh4 = *(const f32x4*)&shv[p * Cn + ob];
#pragma unroll
    for (int ni = 0; ni < 4; ++ni) {
      const int col = col0 + wn * 64 + ni * 16 + nl;
      f32x4 o4;
#pragma unroll
      for (int r = 0; r < 4; ++r) o4[r] = acc[mi][ni][r] + sh4[r];
      *(f32x4*)(yTp + ((size_t)t * NCOLS + col) * Cn + ob) = o4;
    }
  }
}

// ---------------------------------------------------------------------------
// LIF(th=1) + bitpack from yT layout.
// ---------------------------------------------------------------------------
__global__ __launch_bounds__(256) void lif_pack3_T(
    const float* __restrict__ yTq, const float* __restrict__ yTk,
    const float* __restrict__ yTv, u32* __restrict__ bq,
    u32* __restrict__ bk, u32* __restrict__ bv) {
  const int p = blockIdx.x / 294;
  const int idx = (blockIdx.x - p * 294) * 256 + threadIdx.x;  // < 75264
  const float* yT = (p == 0) ? yTq : (p == 1) ? yTk : yTv;
  u32* bits = (p == 0) ? bq : (p == 1) ? bk : bv;
  const int h = idx % Hn, col = idx / Hn;
  const int b = col / Nn, n = col - b * Nn;
  float v[32];
#pragma unroll
  for (int d = 0; d < 32; ++d) v[d] = 0.f;
#pragma unroll
  for (int t = 0; t < Tn; ++t) {
    const f32x4* pp = (const f32x4*)(yT + ((size_t)t * NCOLS + col) * Cn + h * 32);
    u32 m = 0;
#pragma unroll
    for (int q = 0; q < 8; ++q) {
      f32x4 xx = pp[q];
#pragma unroll
      for (int r = 0; r < 4; ++r) {
        const int d = q * 4 + r;
        const float nv = v[d] + (xx[r] - v[d]) * 0.5f;
        const bool s = nv >= 1.0f;
        m |= (u32)(s ? 1u : 0u) << d;
        v[d] = s ? 0.f : nv;
      }
    }
    bits[(size_t)t * BHNn + ((size_t)b * Hn + h) * Nn + n] = m;
  }
}

// ---------------------------------------------------------------------------
// MFMA attention per (t,b,h): y = A·U + diag, where A[n,m]=popc(q&k) (exact
// bf16 int), U[m,d]=p_m*v[m,d] (exact fp32, 3-split bf16), diag adds
// a(n,n)*(1-p_n)*v[n,d]. M=n (13 tiles of 16, pad 208), K=m (7 slabs of 32,
// pad 224), N=d (2 tiles). LDS row stride 40 (16B-aligned, <=2-way banks).
// ---------------------------------------------------------------------------
#define ASTR 40
__global__ __launch_bounds__(256) void attn_mfma(
    const u32* __restrict__ qb, const u32* __restrict__ kb,
    const u32* __restrict__ vb, const float* __restrict__ policy,
    float* __restrict__ yT) {
  __shared__ u32 qs[208], ks[224], vs[224];
  __shared__ float ps[224];
  __shared__ __bf16 psp[3][224];
  __shared__ __bf16 Al[208 * ASTR];
  __shared__ __bf16 Ul[3][32 * ASTR];
  const int gid = blockIdx.x;          // (t*B+b)*H + h
  const int tb = gid / Hn;
  const int h = gid - tb * Hn;
  const int tid = threadIdx.x;
  const int lane = tid & 63, wid = tid >> 6;
  const int quad = lane >> 4, nl = lane & 15;

  // stage bits + policy (zero-padded)
  if (tid < 224) {
    const bool in = tid < Nn;
    qs[tid < 208 ? tid : 0] = 0;  // ensure init; real value below
  }
  for (int i = tid; i < 224; i += 256) {
    const bool in = i < Nn;
    if (i < 208) qs[i] = in ? qb[(size_t)gid * Nn + i] : 0u;
    ks[i] = in ? kb[(size_t)gid * Nn + i] : 0u;
    vs[i] = in ? vb[(size_t)gid * Nn + i] : 0u;
    const float p = in ? policy[(size_t)tb * Nn + i] : 0.f;
    ps[i] = p;
    __bf16 hh, mm, ll;
    split3(p, hh, mm, ll);
    psp[0][i] = hh; psp[1][i] = mm; psp[2][i] = ll;
  }
  __syncthreads();

  f32x4 acc[4][2] = {};   // up to 4 M-tiles x 2 N-tiles per wave

  for (int slab = 0; slab < 7; ++slab) {
    const int m0 = slab * 32;
    // build A-slab: thread = row n (208 used)
    if (tid < 208) {
      const u32 qn = qs[tid];
      __bf16 a32[32];
#pragma unroll
      for (int mk = 0; mk < 32; ++mk)
        a32[mk] = (__bf16)(float)__popc(qn & ks[m0 + mk]);
#pragma unroll
      for (int g = 0; g < 4; ++g)
        *(bf16x8*)&Al[tid * ASTR + g * 8] = *(bf16x8*)&a32[g * 8];
    }
    // build U-slab: thread -> (d', 4 mk)
    {
      const int dp = tid >> 3, mkg = (tid & 7) * 4;
      __bf16 u4[3][4];
#pragma unroll
      for (int j = 0; j < 4; ++j) {
        const int m = m0 + mkg + j;
        const bool bit = (vs[m] >> dp) & 1u;
#pragma unroll
        for (int s = 0; s < 3; ++s)
          u4[s][j] = bit ? psp[s][m] : (__bf16)0.f;
      }
#pragma unroll
      for (int s = 0; s < 3; ++s)
        *(bf16x4v*)&Ul[s][dp * ASTR + mkg] = *(bf16x4v*)u4[s];
    }
    __syncthreads();
    // MFMA: wave wid handles M-tiles {wid, wid+4, wid+8, wid+12<13}
    bf16x8 bfr[3][2];
#pragma unroll
    for (int s = 0; s < 3; ++s)
#pragma unroll
      for (int nt = 0; nt < 2; ++nt)
        bfr[s][nt] = *(const bf16x8*)&Ul[s][(nt * 16 + nl) * ASTR + quad * 8];
#pragma unroll
    for (int mi = 0; mi < 4; ++mi) {
      const int mt = wid + mi * 4;
      if (mt < 13) {
        const bf16x8 af = *(const bf16x8*)&Al[(mt * 16 + nl) * ASTR + quad * 8];
#pragma unroll
        for (int nt = 0; nt < 2; ++nt) {
          f32x4 c = acc[mi][nt];
          c = __builtin_amdgcn_mfma_f32_16x16x32_bf16(af, bfr[0][nt], c, 0, 0, 0);
          c = __builtin_amdgcn_mfma_f32_16x16x32_bf16(af, bfr[1][nt], c, 0, 0, 0);
          c = __builtin_amdgcn_mfma_f32_16x16x32_bf16(af, bfr[2][nt], c, 0, 0, 0);
          acc[mi][nt] = c;
        }
      }
    }
    __syncthreads();
  }
  // epilogue: diag correction + *0.25, store yT[tb*196+n][h*32+d]
#pragma unroll
  for (int mi = 0; mi < 4; ++mi) {
    const int mt = wid + mi * 4;
    if (mt >= 13) continue;
#pragma unroll
    for (int r = 0; r < 4; ++r) {
      const int n = mt * 16 + quad * 4 + r;
      if (n >= Nn) continue;
      const float ann = (float)__popc(qs[n] & ks[n]);
      const float wd = ann * (1.0f - ps[n]);
      const u32 vn = vs[n];
      float* op = yT + ((size_t)tb * Nn + n) * Cn + h * 32;
#pragma unroll
      for (int nt = 0; nt < 2; ++nt) {
        const int d = nt * 16 + nl;
        const float bit = (float)((vn >> d) & 1u);
        op[d] = (acc[mi][nt][r] + wd * bit) * 0.25f;
      }
    }
  }
}

// LIF(0.5) over t on yT layout, emit spikes as exact bf16 -> sp[t][col][c]
__global__ __launch_bounds__(256) void lif05_bf16(
    const float* __restrict__ yT, __bf16* __restrict__ sp) {
  const size_t i4 = ((size_t)blockIdx.x * 256 + threadIdx.x) * 4;  // < BCN
  f32x4 v = {0.f, 0.f, 0.f, 0.f};
#pragma unroll
  for (int t = 0; t < Tn; ++t) {
    f32x4 x = *(const f32x4*)(yT + (size_t)t * BCNn + i4);
    __bf16 s4[4];
#pragma unroll
    for (int r = 0; r < 4; ++r) {
      const float nv = v[r] + (x[r] - v[r]) * 0.5f;
      const bool s = nv >= 0.5f;
      s4[r] = (__bf16)(s ? 1.0f : 0.0f);
      v[r] = s ? 0.f : nv;
    }
    *(bf16x4v*)(sp + (size_t)t * BCNn + i4) = *(bf16x4v*)s4;
  }
}

// ---------------------------------------------------------------------------
// proj GEMM: 3-split iv-scaled bf16 W x binary bf16 spikes (exact).
// ---------------------------------------------------------------------------
__global__ __launch_bounds__(256, 3) void gemm_proj_mfma(
    const __bf16* __restrict__ sp, const __bf16* __restrict__ wspb,
    const float* __restrict__ shv, float* __restrict__ z)
{
  __shared__ __bf16 Asw[3][128][32];
  __shared__ __bf16 Bsw[128][32];
  const int bid = blockIdx.x;
  const int xcd = bid & 7, slot = bid >> 3;      // slot 0..74
  const int gl = slot / 3, mt = slot - gl * 3;
  const int group = xcd * 25 + gl;
  if (group >= 196) return;
  const int colt = group % 49, t = group / 49;
  const int col0 = colt * 128, o0 = mt * 128;
  const int tid = threadIdx.x, lane = tid & 63, wid = tid >> 6;
  const int wm = wid >> 1, wn = wid & 1;
  const int quad = lane >> 4, nl = lane & 15;
  const __bf16* Bg = sp + ((size_t)t * NCOLS + col0) * Cn;

  f32x4 acc[4][4] = {};
  bf16x8 aval[6], bval[2];
#pragma unroll
  for (int i = 0; i < 6; ++i) {
    const int u = tid + i * 256, s = u >> 9, rem = u & 511;
    const int row = rem >> 2, kb = rem & 3;
    aval[i] = *(const bf16x8*)(wspb + (size_t)s * WSZ + (size_t)(o0 + row) * Cn + kb * 8);
  }
#pragma unroll
  for (int i = 0; i < 2; ++i) {
    const int u = tid + i * 256, row = u >> 2, kb = u & 3;
    bval[i] = *(const bf16x8*)(Bg + (size_t)row * Cn + kb * 8);
  }

  for (int kk = 0; kk < 12; ++kk) {
    __syncthreads();
#pragma unroll
    for (int i = 0; i < 6; ++i) {
      const int u = tid + i * 256, s = u >> 9, rem = u & 511;
      const int row = rem >> 2, kb = rem & 3;
      const int kbp = kb ^ ((row >> 1) & 3);
      *(bf16x8*)&Asw[s][row][kbp * 8] = aval[i];
    }
#pragma unroll
    for (int i = 0; i < 2; ++i) {
      const int u = tid + i * 256, row = u >> 2, kb = u & 3;
      const int kbp = kb ^ ((row >> 1) & 3);
      *(bf16x8*)&Bsw[row][kbp * 8] = bval[i];
    }
    __syncthreads();
    if (kk < 11) {
      const int k0n = (kk + 1) * 32;
#pragma unroll
      for (int i = 0; i < 6; ++i) {
        const int u = tid + i * 256, s = u >> 9, rem = u & 511;
        const int row = rem >> 2, kb = rem & 3;
        aval[i] = *(const bf16x8*)(wspb + (size_t)s * WSZ +
                                   (size_t)(o0 + row) * Cn + k0n + kb * 8);
      }
#pragma unroll
      for (int i = 0; i < 2; ++i) {
        const int u = tid + i * 256, row = u >> 2, kb = u & 3;
        bval[i] = *(const bf16x8*)(Bg + (size_t)row * Cn + k0n + kb * 8);
      }
    }
    bf16x8 af[3][4], bfr[4];
#pragma unroll
    for (int i = 0; i < 4; ++i) {
      const int ra = wm * 64 + i * 16 + nl;
      const int rb = wn * 64 + i * 16 + nl;
      const int ka = (quad ^ ((ra >> 1) & 3)) * 8;
      const int kb2 = (quad ^ ((rb >> 1) & 3)) * 8;
      bfr[i] = *(const bf16x8*)&Bsw[rb][kb2];
#pragma unroll
      for (int s = 0; s < 3; ++s)
        af[s][i] = *(const bf16x8*)&Asw[s][ra][ka];
    }
#pragma unroll
    for (int mi = 0; mi < 4; ++mi)
#pragma unroll
      for (int ni = 0; ni < 4; ++ni) {
        f32x4 c = acc[mi][ni];
        c = __builtin_amdgcn_mfma_f32_16x16x32_bf16(af[0][mi], bfr[ni], c, 0, 0, 0);
        c = __builtin_amdgcn_mfma_f32_16x16x32_bf16(af[1][mi], bfr[ni], c, 0, 0, 0);
        c = __builtin_amdgcn_mfma_f32_16x16x32_bf16(af[2][mi], bfr[ni], c, 0, 0, 0);
        acc[mi][ni] = c;
      }
  }
#pragma unroll
  for (int mi = 0; mi < 4; ++mi) {
    const int ob = o0 + wm * 64 + mi * 16 + quad * 4;
    const f32x4 sh4 = *(const f32x4*)&shv[3 * Cn + ob];
#pragma unroll
    for (int ni = 0; ni < 4; ++ni) {
      const int col = col0 + wn * 64 + ni * 16 + nl;
      const int b = col / Nn, nn = col - b * Nn;
      float* zp = z + (size_t)t * BCNn + (size_t)b * CNn + nn;
#pragma unroll
      for (int r = 0; r < 4; ++r)
        zp[(size_t)(ob + r) * Nn] = acc[mi][ni][r] + sh4[r];
    }
  }
}

// final LIF(1.0): z [t,b,o,n] fp32 -> out binary fp32
__global__ __launch_bounds__(256) void lif_out_v4(
    const float* __restrict__ z, float* __restrict__ out) {
  const size_t i4 = ((size_t)blockIdx.x * 256 + threadIdx.x) * 4;
  f32x4 v = {0.f, 0.f, 0.f, 0.f};
#pragma unroll
  for (int t = 0; t < Tn; ++t) {
    f32x4 x = *(const f32x4*)(z + (size_t)t * BCNn + i4);
    f32x4 o4;
#pragma unroll
    for (int r = 0; r < 4; ++r) {
      const float nv = v[r] + (x[r] - v[r]) * 0.5f;
      const bool s = nv >= 1.0f;
      o4[r] = s ? 1.0f : 0.0f;
      v[r] = s ? 0.f : nv;
    }
    *(f32x4*)(out + (size_t)t * BCNn + i4) = o4;
  }
}

// ===========================================================================
extern "C" void kernel_launch(void* const* d_in, const int* in_sizes, int n_in,
                              void* d_out, int out_size, void* d_ws, size_t ws_size,
                              hipStream_t stream) {
  const float* x      = (const float*)d_in[0];
  const float* policy = (const float*)d_in[1];
  const float* qw = (const float*)d_in[2];
  const float* qg = (const float*)d_in[3];
  const float* qb_ = (const float*)d_in[4];
  const float* qm = (const float*)d_in[5];
  const float* qv = (const float*)d_in[6];
  const float* kw = (const float*)d_in[7];
  const float* kg = (const float*)d_in[8];
  const float* kbe = (const float*)d_in[9];
  const float* km = (const float*)d_in[10];
  const float* kv = (const float*)d_in[11];
  const float* vw = (const float*)d_in[12];
  const float* vg = (const float*)d_in[13];
  const float* vbe = (const float*)d_in[14];
  const float* vm = (const float*)d_in[15];
  const float* vv = (const float*)d_in[16];
  const float* pw = (const float*)d_in[17];
  const float* pg = (const float*)d_in[18];
  const float* pbe = (const float*)d_in[19];
  const float* pm = (const float*)d_in[20];
  const float* pv = (const float*)d_in[21];
  const float* pbias = (const float*)d_in[22];
  float* out = (float*)d_out;

  char* base = (char*)d_ws;
  _Float16* xs   = (_Float16*)base;                           // 38,535,168 (2 f16 planes)
  _Float16* wsp16 = (_Float16*)(base + (size_t)TBCNn * 4);    //  1,769,472
  __bf16* wspb   = (__bf16*)((char*)wsp16 + (size_t)6 * WSZ * 2); // 884,736
  float* shv     = (float*)((char*)wspb + (size_t)3 * WSZ * 2);   //   6,144
  float* yTq     = (float*)((char*)shv + 4 * Cn * 4);         // 38,535,168 x3
  float* yTk = yTq + TBCNn;
  float* yTv = yTk + TBCNn;
  u32* bq = (u32*)(yTv + TBCNn);                              //  3,612,672
  u32* bk = bq + PBITS;
  u32* bv = bk + PBITS;
  __bf16* sp = (__bf16*)yTk;   // alias: yTk dead after pack
  float* z   = yTv;            // alias: yTv dead after pack

  WSplitArgs wa;
  wa.w[0] = qw; wa.g[0] = qg; wa.be[0] = qb_; wa.mu[0] = qm; wa.va[0] = qv;
  wa.w[1] = kw; wa.g[1] = kg; wa.be[1] = kbe; wa.mu[1] = km; wa.va[1] = kv;
  wa.w[2] = vw; wa.g[2] = vg; wa.be[2] = vbe; wa.mu[2] = vm; wa.va[2] = vv;
  wa.w[3] = pw; wa.g[3] = pg; wa.be[3] = pbe; wa.mu[3] = pm; wa.va[3] = pv;
  wa.bias = pbias;
  split_w<<<2304, 256, 0, stream>>>(wa, wsp16, wspb, shv);
  transpose_split_x<<<dim3(4, 32, 12), 256, 0, stream>>>(x, xs);

  gemm_qkv_f16<<<1800, 256, 0, stream>>>(xs, wsp16, shv, yTq);
  lif_pack3_T<<<882, 256, 0, stream>>>(yTq, yTk, yTv, bq, bk, bv);
  // MFMA attention (t-parallel) writes y*0.25 into yTq (dead after pack)
  attn_mfma<<<Tn * Bn * Hn, 256, 0, stream>>>(bq, bk, bv, policy, yTq);
  lif05_bf16<<<BCNn / 1024, 256, 0, stream>>>(yTq, sp);
  gemm_proj_mfma<<<600, 256, 0, stream>>>(sp, wspb, shv, z);
  lif_out_v4<<<BCNn / 1024, 256, 0, stream>>>(z, out);
}

// Round 2
// 340.058 us; speedup vs baseline: 1.0732x; 1.0509x over previous
//
#include <hip/hip_runtime.h>

typedef unsigned int u32;
typedef __bf16 bf16x8 __attribute__((ext_vector_type(8)));
typedef __bf16 bf16x4v __attribute__((ext_vector_type(4)));
typedef _Float16 f16x8 __attribute__((ext_vector_type(8)));
typedef float f32x4 __attribute__((ext_vector_type(4)));

#define Tn 4
#define Bn 32
#define Cn 384
#define Nn 196
#define Hn 12
#define CNn (Cn*Nn)         // 75264
#define BCNn (Bn*CNn)       // 2408448
#define BHNn (Bn*Hn*Nn)     // 75264
#define PBITS (Tn*BHNn)     // 301056
#define TBCNn (Tn*BCNn)     // 9633792
#define NCOLS 6272          // B*N
#define WSZ 147456          // 384*384

// fp32 -> 3-way bf16 split (residual ~2^-24 rel)
__device__ __forceinline__ void split3(float v, __bf16& h, __bf16& m, __bf16& l) {
  h = (__bf16)v;  float r = v - (float)h;
  m = (__bf16)r;  float r2 = r - (float)m;
  l = (__bf16)r2;
}
// fp32 -> 2-way f16 split (residual ~2^-22 rel)
__device__ __forceinline__ void split2h(float v, _Float16& h, _Float16& l) {
  h = (_Float16)v;  l = (_Float16)(v - (float)h);
}

// direct global->LDS 16B copy: lane i lands at ldsbase + i*16 (wave-uniform base)
__device__ __forceinline__ void gl_lds16(const void* g, void* l) {
  __builtin_amdgcn_global_load_lds(
      (const __attribute__((address_space(1))) unsigned int*)g,
      (__attribute__((address_space(3))) unsigned int*)l, 16, 0, 0);
}

// ---------------------------------------------------------------------------
// W split: QKV (p<3) -> iv-scaled f16 2-split; proj -> iv-scaled bf16 3-split.
// ---------------------------------------------------------------------------
struct WSplitArgs {
  const float* w[4]; const float* g[4]; const float* be[4];
  const float* mu[4]; const float* va[4]; const float* bias;
};
__global__ __launch_bounds__(256) void split_w(
    WSplitArgs a, _Float16* __restrict__ wsp16, __bf16* __restrict__ wspb,
    float* __restrict__ shv) {
  const int i = blockIdx.x * 256 + threadIdx.x;   // < 589824
  const int p = i / WSZ, r = i - p * WSZ;
  const int o = r / Cn;
  const float iv = a.g[p][o] / sqrtf(a.va[p][o] + 1e-5f);
  const float wv = a.w[p][r] * iv;
  if (p < 3) {
    _Float16 h, l;
    split2h(wv, h, l);
    wsp16[(size_t)(p * 2 + 0) * WSZ + r] = h;
    wsp16[(size_t)(p * 2 + 1) * WSZ + r] = l;
  } else {
    __bf16 h, m, l;
    split3(wv, h, m, l);
    wspb[(size_t)0 * WSZ + r] = h;
    wspb[(size_t)1 * WSZ + r] = m;
    wspb[(size_t)2 * WSZ + r] = l;
  }
  if (r - o * Cn == 0) {
    float sh = a.be[p][o] - a.mu[p][o] * iv;
    if (p == 3) sh += a.bias[o] * iv;
    shv[p * Cn + o] = sh;
  }
}

// ---------------------------------------------------------------------------
// x [t,b,c,n] -> pre-split f16 planes xs[s][t][col=(b,n)][c], s=h/l.
// ---------------------------------------------------------------------------
__global__ __launch_bounds__(256) void transpose_split_x(
    const float* __restrict__ x, _Float16* __restrict__ xs) {
  __shared__ float tile[49 * 130];
  const int t = blockIdx.x, b = blockIdx.y;
  const int ct = blockIdx.z >> 2, nch = blockIdx.z & 3;
  const int c0 = ct * 128, n0 = nch * 49;
  const int tid = threadIdx.x;
  for (int idx = tid; idx < 49 * 128; idx += 256) {
    const int n = idx % 49, c = idx / 49;
    tile[n * 130 + c] = x[(size_t)t * BCNn + (size_t)b * CNn +
                          (size_t)(c0 + c) * Nn + n0 + n];
  }
  __syncthreads();
  for (int idx = tid; idx < 49 * 64; idx += 256) {
    const int cp = idx & 63, n = idx >> 6;
    const float v0 = tile[n * 130 + cp * 2];
    const float v1 = tile[n * 130 + cp * 2 + 1];
    _Float16 h0, l0, h1, l1;
    split2h(v0, h0, l0);
    split2h(v1, h1, l1);
    const size_t col = (size_t)t * NCOLS + (size_t)b * Nn + n0 + n;
    union { _Float16 f[2]; u32 u; } uh, ul;
    uh.f[0] = h0; uh.f[1] = h1;
    ul.f[0] = l0; ul.f[1] = l1;
    ((u32*)(xs + col * Cn + c0))[cp] = uh.u;
    ((u32*)(xs + (size_t)TBCNn + col * Cn + c0))[cp] = ul.u;
  }
}

// ---------------------------------------------------------------------------
// FUSED QKV GEMM + LIF(1.0) + bitpack. One block per (colt, p, mt) = 441
// blocks; t-loop inside so the LIF membrane state lives in registers and the
// fp32 yT round-trip (231 MB) disappears. MFMA inner loop is instruction-
// identical to the validated R1 kernel. Epilogue packs spike bits per
// (col, h-word) via cross-quad shfl-OR, writes 3.6 MB of bits total.
// ---------------------------------------------------------------------------
__global__ __launch_bounds__(256, 2) void gemm_qkv_lif(
    const _Float16* __restrict__ xs,    // [2][t][col][c] f16 pre-split
    const _Float16* __restrict__ wsp16, // [3][2][o][c] iv-scaled f16 2-split
    const float* __restrict__ shv,      // [4][o]
    u32* __restrict__ bq, u32* __restrict__ bk, u32* __restrict__ bv)
{
  __shared__ _Float16 Asw[2][128][32];
  __shared__ _Float16 Bsw[2][128][32];
  // bijective chunked XCD swizzle over 441 workgroups (q=55, r=1):
  // 9 consecutive wgid (the 9 (p,mt) variants of one colt) share an XCD -> B
  // panel L2 reuse.
  const int orig = blockIdx.x;
  const int xcd = orig & 7, i8 = orig >> 3;
  const int wgid = (xcd == 0) ? i8 : (56 + (xcd - 1) * 55 + i8);
  const int colt = wgid / 9, v = wgid - colt * 9;
  const int col0 = colt * 128;
  const int p = v / 3, mt = v - p * 3;
  const int o0 = mt * 128;
  const int tid = threadIdx.x, lane = tid & 63, wid = tid >> 6;
  const int wm = wid >> 1, wn = wid & 1;
  const int quad = lane >> 4, nl = lane & 15;
  u32* __restrict__ bits = (p == 0) ? bq : (p == 1) ? bk : bv;

  // per-lane staging source addresses (pre-swizzled so linear LDS dest +
  // XOR-swizzled fragment reads are conflict-free; rule #21).
  const char* aSrc[4];
  const char* bSrc0[4];
#pragma unroll
  for (int i = 0; i < 4; ++i) {
    const int c = i * 256 + wid * 64 + lane;
    const int s = c >> 9, row = (c >> 2) & 127, kb = c & 3;
    const int kbs = kb ^ ((row >> 1) & 3);
    aSrc[i] = (const char*)(wsp16 + (size_t)(p * 2 + s) * WSZ +
                            (size_t)(o0 + row) * Cn + kbs * 8);
    bSrc0[i] = (const char*)(xs + (size_t)s * TBCNn +
                             (size_t)(col0 + row) * Cn + kbs * 8);
  }
  char* aDst = (char*)&Asw[0][0][0] + wid * 1024;
  char* bDst = (char*)&Bsw[0][0][0] + wid * 1024;

  // BN shift, t-invariant
  f32x4 sh[4];
#pragma unroll
  for (int mi = 0; mi < 4; ++mi)
    sh[mi] = *(const f32x4*)&shv[p * Cn + o0 + wm * 64 + mi * 16 + quad * 4];

  // LIF membrane state, persistent across t
  float vst[4][4][4] = {};

  for (int t = 0; t < Tn; ++t) {
    const size_t tOff = (size_t)t * ((size_t)NCOLS * Cn * 2);  // bytes
    f32x4 acc[4][4] = {};
    for (int kk = 0; kk < 12; ++kk) {
      const int koff = kk * 64;   // 32 f16 = 64 bytes per K-step
#pragma unroll
      for (int i = 0; i < 4; ++i) {
        gl_lds16(aSrc[i] + koff, aDst + i * 4096);
        gl_lds16(bSrc0[i] + tOff + koff, bDst + i * 4096);
      }
      __syncthreads();
      f16x8 af[2][4], bfr[2][4];
#pragma unroll
      for (int i = 0; i < 4; ++i) {
        const int ra = wm * 64 + i * 16 + nl;
        const int rb = wn * 64 + i * 16 + nl;
        const int ka = (quad ^ ((ra >> 1) & 3)) * 8;
        const int kb2 = (quad ^ ((rb >> 1) & 3)) * 8;
#pragma unroll
        for (int s = 0; s < 2; ++s) {
          af[s][i]  = *(const f16x8*)&Asw[s][ra][ka];
          bfr[s][i] = *(const f16x8*)&Bsw[s][rb][kb2];
        }
      }
#pragma unroll
      for (int mi = 0; mi < 4; ++mi)
#pragma unroll
        for (int ni = 0; ni < 4; ++ni) {
          f32x4 c = acc[mi][ni];
          c = __builtin_amdgcn_mfma_f32_16x16x32_f16(af[0][mi], bfr[0][ni], c, 0, 0, 0);
          c = __builtin_amdgcn_mfma_f32_16x16x32_f16(af[0][mi], bfr[1][ni], c, 0, 0, 0);
          c = __builtin_amdgcn_mfma_f32_16x16x32_f16(af[1][mi], bfr[0][ni], c, 0, 0, 0);
          acc[mi][ni] = c;
        }
      __syncthreads();
    }
    // epilogue for this t: LIF + bitpack (no LDS use -> safe vs next t stage)
#pragma unroll
    for (int ni = 0; ni < 4; ++ni) {
      u32 w0 = 0, w1 = 0;
#pragma unroll
      for (int mi = 0; mi < 4; ++mi) {
#pragma unroll
        for (int r = 0; r < 4; ++r) {
          const float y = acc[mi][ni][r] + sh[mi][r];
          const float vv = vst[mi][ni][r];
          const float nv = vv + (y - vv) * 0.5f;
          const bool s = nv >= 1.0f;
          vst[mi][ni][r] = s ? 0.f : nv;
          const u32 b1 = s ? 1u : 0u;
          const int pos = ((mi & 1) << 4) + (quad << 2) + r;
          if (mi < 2) w0 |= b1 << pos; else w1 |= b1 << pos;
        }
      }
      // OR across the 4 quads (lanes nl, nl+16, nl+32, nl+48)
      w0 |= __shfl_xor(w0, 16); w0 |= __shfl_xor(w0, 32);
      w1 |= __shfl_xor(w1, 16); w1 |= __shfl_xor(w1, 32);
      if (quad == 0) {
        const int col = col0 + wn * 64 + ni * 16 + nl;
        const int bb = col / Nn, nn = col - bb * Nn;
        u32* bp = bits + (size_t)t * BHNn +
                  ((size_t)bb * Hn + (mt * 4 + wm * 2)) * Nn + nn;
        bp[0] = w0;       // h = mt*4 + wm*2
        bp[Nn] = w1;      // h = mt*4 + wm*2 + 1
      }
    }
  }
}

// ---------------------------------------------------------------------------
// FUSED MFMA attention + LIF(0.5). One block per (b,h) = 384 blocks; t-loop
// inside so LIF state stays in registers; emits bf16 spikes directly to sp
// (eliminates the fp32 y write + lif05 pass, -58 MB HBM).
// y = A.U + diag, A[n,m]=popc(q&k) (exact bf16 int), U[m,d]=p_m*v[m,d]
// (exact fp32, 3-split bf16), diag adds a(n,n)*(1-p_n)*v[n,d].
// ---------------------------------------------------------------------------
#define ASTR 40
__global__ __launch_bounds__(256) void attn_lif(
    const u32* __restrict__ qb, const u32* __restrict__ kb,
    const u32* __restrict__ vb, const float* __restrict__ policy,
    __bf16* __restrict__ sp) {
  __shared__ u32 qs[208], ks[224], vs_[224];
  __shared__ float ps[224];
  __shared__ __bf16 psp[3][224];
  __shared__ __bf16 Al[208 * ASTR];
  __shared__ __bf16 Ul[3][32 * ASTR];
  const int bh = blockIdx.x;           // b*H + h
  const int bN = bh / Hn;
  const int h = bh - bN * Hn;
  const int tid = threadIdx.x;
  const int lane = tid & 63, wid = tid >> 6;
  const int quad = lane >> 4, nl = lane & 15;

  float vst[4][2][4] = {};   // LIF(0.5) membrane, persistent across t

  for (int t = 0; t < Tn; ++t) {
    const int tb = t * Bn + bN;
    const int gid = tb * Hn + h;
    if (t) __syncthreads();   // prior epilogue reads qs/vs_/ps done
    // stage bits + policy (zero-padded)
    for (int i = tid; i < 224; i += 256) {
      const bool in = i < Nn;
      if (i < 208) qs[i] = in ? qb[(size_t)gid * Nn + i] : 0u;
      ks[i] = in ? kb[(size_t)gid * Nn + i] : 0u;
      vs_[i] = in ? vb[(size_t)gid * Nn + i] : 0u;
      const float p = in ? policy[(size_t)tb * Nn + i] : 0.f;
      ps[i] = p;
      __bf16 hh, mm, ll;
      split3(p, hh, mm, ll);
      psp[0][i] = hh; psp[1][i] = mm; psp[2][i] = ll;
    }
    __syncthreads();

    f32x4 acc[4][2] = {};

    for (int slab = 0; slab < 7; ++slab) {
      const int m0 = slab * 32;
      if (tid < 208) {
        const u32 qn = qs[tid];
        __bf16 a32[32];
#pragma unroll
        for (int mk = 0; mk < 32; ++mk)
          a32[mk] = (__bf16)(float)__popc(qn & ks[m0 + mk]);
#pragma unroll
        for (int g = 0; g < 4; ++g)
          *(bf16x8*)&Al[tid * ASTR + g * 8] = *(bf16x8*)&a32[g * 8];
      }
      {
        const int dp = tid >> 3, mkg = (tid & 7) * 4;
        __bf16 u4[3][4];
#pragma unroll
        for (int j = 0; j < 4; ++j) {
          const int m = m0 + mkg + j;
          const bool bit = (vs_[m] >> dp) & 1u;
#pragma unroll
          for (int s = 0; s < 3; ++s)
            u4[s][j] = bit ? psp[s][m] : (__bf16)0.f;
        }
#pragma unroll
        for (int s = 0; s < 3; ++s)
          *(bf16x4v*)&Ul[s][dp * ASTR + mkg] = *(bf16x4v*)u4[s];
      }
      __syncthreads();
      bf16x8 bfr[3][2];
#pragma unroll
      for (int s = 0; s < 3; ++s)
#pragma unroll
        for (int nt = 0; nt < 2; ++nt)
          bfr[s][nt] = *(const bf16x8*)&Ul[s][(nt * 16 + nl) * ASTR + quad * 8];
#pragma unroll
      for (int mi = 0; mi < 4; ++mi) {
        const int mt2 = wid + mi * 4;
        if (mt2 < 13) {
          const bf16x8 af = *(const bf16x8*)&Al[(mt2 * 16 + nl) * ASTR + quad * 8];
#pragma unroll
          for (int nt = 0; nt < 2; ++nt) {
            f32x4 c = acc[mi][nt];
            c = __builtin_amdgcn_mfma_f32_16x16x32_bf16(af, bfr[0][nt], c, 0, 0, 0);
            c = __builtin_amdgcn_mfma_f32_16x16x32_bf16(af, bfr[1][nt], c, 0, 0, 0);
            c = __builtin_amdgcn_mfma_f32_16x16x32_bf16(af, bfr[2][nt], c, 0, 0, 0);
            acc[mi][nt] = c;
          }
        }
      }
      __syncthreads();
    }
    // epilogue: diag + *0.25, fused LIF(0.5), bf16 spike store
#pragma unroll
    for (int mi = 0; mi < 4; ++mi) {
      const int mt2 = wid + mi * 4;
      if (mt2 >= 13) continue;
#pragma unroll
      for (int r = 0; r < 4; ++r) {
        const int n = mt2 * 16 + quad * 4 + r;
        if (n >= Nn) continue;
        const float ann = (float)__popc(qs[n] & ks[n]);
        const float wd = ann * (1.0f - ps[n]);
        const u32 vn = vs_[n];
        __bf16* op = sp + (size_t)t * BCNn + ((size_t)bN * Nn + n) * Cn + h * 32;
#pragma unroll
        for (int nt = 0; nt < 2; ++nt) {
          const int d = nt * 16 + nl;
          const float bit = (float)((vn >> d) & 1u);
          const float y = (acc[mi][nt][r] + wd * bit) * 0.25f;
          const float vv = vst[mi][nt][r];
          const float nv = vv + (y - vv) * 0.5f;
          const bool s = nv >= 0.5f;
          vst[mi][nt][r] = s ? 0.f : nv;
          op[d] = (__bf16)(s ? 1.0f : 0.0f);
        }
      }
    }
  }
}

// ---------------------------------------------------------------------------
// proj GEMM: 3-split iv-scaled bf16 W x binary bf16 spikes (exact).
// ---------------------------------------------------------------------------
__global__ __launch_bounds__(256, 3) void gemm_proj_mfma(
    const __bf16* __restrict__ sp, const __bf16* __restrict__ wspb,
    const float* __restrict__ shv, float* __restrict__ z)
{
  __shared__ __bf16 Asw[3][128][32];
  __shared__ __bf16 Bsw[128][32];
  const int bid = blockIdx.x;
  const int xcd = bid & 7, slot = bid >> 3;      // slot 0..74
  const int gl = slot / 3, mt = slot - gl * 3;
  const int group = xcd * 25 + gl;
  if (group >= 196) return;
  const int colt = group % 49, t = group / 49;
  const int col0 = colt * 128, o0 = mt * 128;
  const int tid = threadIdx.x, lane = tid & 63, wid = tid >> 6;
  const int wm = wid >> 1, wn = wid & 1;
  const int quad = lane >> 4, nl = lane & 15;
  const __bf16* Bg = sp + ((size_t)t * NCOLS + col0) * Cn;

  f32x4 acc[4][4] = {};
  bf16x8 aval[6], bval[2];
#pragma unroll
  for (int i = 0; i < 6; ++i) {
    const int u = tid + i * 256, s = u >> 9, rem = u & 511;
    const int row = rem >> 2, kb = rem & 3;
    aval[i] = *(const bf16x8*)(wspb + (size_t)s * WSZ + (size_t)(o0 + row) * Cn + kb * 8);
  }
#pragma unroll
  for (int i = 0; i < 2; ++i) {
    const int u = tid + i * 256, row = u >> 2, kb = u & 3;
    bval[i] = *(const bf16x8*)(Bg + (size_t)row * Cn + kb * 8);
  }

  for (int kk = 0; kk < 12; ++kk) {
    __syncthreads();
#pragma unroll
    for (int i = 0; i < 6; ++i) {
      const int u = tid + i * 256, s = u >> 9, rem = u & 511;
      const int row = rem >> 2, kb = rem & 3;
      const int kbp = kb ^ ((row >> 1) & 3);
      *(bf16x8*)&Asw[s][row][kbp * 8] = aval[i];
    }
#pragma unroll
    for (int i = 0; i < 2; ++i) {
      const int u = tid + i * 256, row = u >> 2, kb = u & 3;
      const int kbp = kb ^ ((row >> 1) & 3);
      *(bf16x8*)&Bsw[row][kbp * 8] = bval[i];
    }
    __syncthreads();
    if (kk < 11) {
      const int k0n = (kk + 1) * 32;
#pragma unroll
      for (int i = 0; i < 6; ++i) {
        const int u = tid + i * 256, s = u >> 9, rem = u & 511;
        const int row = rem >> 2, kb = rem & 3;
        aval[i] = *(const bf16x8*)(wspb + (size_t)s * WSZ +
                                   (size_t)(o0 + row) * Cn + k0n + kb * 8);
      }
#pragma unroll
      for (int i = 0; i < 2; ++i) {
        const int u = tid + i * 256, row = u >> 2, kb = u & 3;
        bval[i] = *(const bf16x8*)(Bg + (size_t)row * Cn + k0n + kb * 8);
      }
    }
    bf16x8 af[3][4], bfr[4];
#pragma unroll
    for (int i = 0; i < 4; ++i) {
      const int ra = wm * 64 + i * 16 + nl;
      const int rb = wn * 64 + i * 16 + nl;
      const int ka = (quad ^ ((ra >> 1) & 3)) * 8;
      const int kb2 = (quad ^ ((rb >> 1) & 3)) * 8;
      bfr[i] = *(const bf16x8*)&Bsw[rb][kb2];
#pragma unroll
      for (int s = 0; s < 3; ++s)
        af[s][i] = *(const bf16x8*)&Asw[s][ra][ka];
    }
#pragma unroll
    for (int mi = 0; mi < 4; ++mi)
#pragma unroll
      for (int ni = 0; ni < 4; ++ni) {
        f32x4 c = acc[mi][ni];
        c = __builtin_amdgcn_mfma_f32_16x16x32_bf16(af[0][mi], bfr[ni], c, 0, 0, 0);
        c = __builtin_amdgcn_mfma_f32_16x16x32_bf16(af[1][mi], bfr[ni], c, 0, 0, 0);
        c = __builtin_amdgcn_mfma_f32_16x16x32_bf16(af[2][mi], bfr[ni], c, 0, 0, 0);
        acc[mi][ni] = c;
      }
  }
#pragma unroll
  for (int mi = 0; mi < 4; ++mi) {
    const int ob = o0 + wm * 64 + mi * 16 + quad * 4;
    const f32x4 sh4 = *(const f32x4*)&shv[3 * Cn + ob];
#pragma unroll
    for (int ni = 0; ni < 4; ++ni) {
      const int col = col0 + wn * 64 + ni * 16 + nl;
      const int b = col / Nn, nn = col - b * Nn;
      float* zp = z + (size_t)t * BCNn + (size_t)b * CNn + nn;
#pragma unroll
      for (int r = 0; r < 4; ++r)
        zp[(size_t)(ob + r) * Nn] = acc[mi][ni][r] + sh4[r];
    }
  }
}

// final LIF(1.0): z [t,b,o,n] fp32 -> out binary fp32
__global__ __launch_bounds__(256) void lif_out_v4(
    const float* __restrict__ z, float* __restrict__ out) {
  const size_t i4 = ((size_t)blockIdx.x * 256 + threadIdx.x) * 4;
  f32x4 v = {0.f, 0.f, 0.f, 0.f};
#pragma unroll
  for (int t = 0; t < Tn; ++t) {
    f32x4 x = *(const f32x4*)(z + (size_t)t * BCNn + i4);
    f32x4 o4;
#pragma unroll
    for (int r = 0; r < 4; ++r) {
      const float nv = v[r] + (x[r] - v[r]) * 0.5f;
      const bool s = nv >= 1.0f;
      o4[r] = s ? 1.0f : 0.0f;
      v[r] = s ? 0.f : nv;
    }
    *(f32x4*)(out + (size_t)t * BCNn + i4) = o4;
  }
}

// ===========================================================================
extern "C" void kernel_launch(void* const* d_in, const int* in_sizes, int n_in,
                              void* d_out, int out_size, void* d_ws, size_t ws_size,
                              hipStream_t stream) {
  const float* x      = (const float*)d_in[0];
  const float* policy = (const float*)d_in[1];
  const float* qw = (const float*)d_in[2];
  const float* qg = (const float*)d_in[3];
  const float* qb_ = (const float*)d_in[4];
  const float* qm = (const float*)d_in[5];
  const float* qv = (const float*)d_in[6];
  const float* kw = (const float*)d_in[7];
  const float* kg = (const float*)d_in[8];
  const float* kbe = (const float*)d_in[9];
  const float* km = (const float*)d_in[10];
  const float* kv = (const float*)d_in[11];
  const float* vw = (const float*)d_in[12];
  const float* vg = (const float*)d_in[13];
  const float* vbe = (const float*)d_in[14];
  const float* vm = (const float*)d_in[15];
  const float* vv = (const float*)d_in[16];
  const float* pw = (const float*)d_in[17];
  const float* pg = (const float*)d_in[18];
  const float* pbe = (const float*)d_in[19];
  const float* pm = (const float*)d_in[20];
  const float* pv = (const float*)d_in[21];
  const float* pbias = (const float*)d_in[22];
  float* out = (float*)d_out;

  char* base = (char*)d_ws;
  _Float16* xs   = (_Float16*)base;                               // 38,535,168
  _Float16* wsp16 = (_Float16*)(base + (size_t)TBCNn * 4);        //  1,769,472
  __bf16* wspb   = (__bf16*)((char*)wsp16 + (size_t)6 * WSZ * 2); //    884,736
  float* shv     = (float*)((char*)wspb + (size_t)3 * WSZ * 2);   //      6,144
  u32* bq        = (u32*)((char*)shv + 4 * Cn * 4);               //  1,204,224 x3
  u32* bk = bq + PBITS;
  u32* bv = bk + PBITS;
  __bf16* sp     = (__bf16*)(bv + PBITS);                         // 19,267,584
  float* z       = (float*)((char*)sp + (size_t)TBCNn * 2);       // 38,535,168

  WSplitArgs wa;
  wa.w[0] = qw; wa.g[0] = qg; wa.be[0] = qb_; wa.mu[0] = qm; wa.va[0] = qv;
  wa.w[1] = kw; wa.g[1] = kg; wa.be[1] = kbe; wa.mu[1] = km; wa.va[1] = kv;
  wa.w[2] = vw; wa.g[2] = vg; wa.be[2] = vbe; wa.mu[2] = vm; wa.va[2] = vv;
  wa.w[3] = pw; wa.g[3] = pg; wa.be[3] = pbe; wa.mu[3] = pm; wa.va[3] = pv;
  wa.bias = pbias;
  split_w<<<2304, 256, 0, stream>>>(wa, wsp16, wspb, shv);
  transpose_split_x<<<dim3(4, 32, 12), 256, 0, stream>>>(x, xs);

  gemm_qkv_lif<<<441, 256, 0, stream>>>(xs, wsp16, shv, bq, bk, bv);
  attn_lif<<<Bn * Hn, 256, 0, stream>>>(bq, bk, bv, policy, sp);
  gemm_proj_mfma<<<600, 256, 0, stream>>>(sp, wspb, shv, z);
  lif_out_v4<<<BCNn / 1024, 256, 0, stream>>>(z, out);
}

// Round 3
// 321.965 us; speedup vs baseline: 1.1335x; 1.0562x over previous
//
#include <hip/hip_runtime.h>

typedef unsigned int u32;
typedef __bf16 bf16x8 __attribute__((ext_vector_type(8)));
typedef __bf16 bf16x4v __attribute__((ext_vector_type(4)));
typedef _Float16 f16x8 __attribute__((ext_vector_type(8)));
typedef float f32x4 __attribute__((ext_vector_type(4)));

#define Tn 4
#define Bn 32
#define Cn 384
#define Nn 196
#define Hn 12
#define CNn (Cn*Nn)         // 75264
#define BCNn (Bn*CNn)       // 2408448
#define BHNn (Bn*Hn*Nn)     // 75264
#define PBITS (Tn*BHNn)     // 301056
#define TBCNn (Tn*BCNn)     // 9633792
#define NCOLS 6272          // B*N
#define WSZ 147456          // 384*384

// fp32 -> 3-way bf16 split (residual ~2^-24 rel)
__device__ __forceinline__ void split3(float v, __bf16& h, __bf16& m, __bf16& l) {
  h = (__bf16)v;  float r = v - (float)h;
  m = (__bf16)r;  float r2 = r - (float)m;
  l = (__bf16)r2;
}
// fp32 -> 2-way f16 split (residual ~2^-22 rel)
__device__ __forceinline__ void split2h(float v, _Float16& h, _Float16& l) {
  h = (_Float16)v;  l = (_Float16)(v - (float)h);
}

// direct global->LDS 16B copy: lane i lands at ldsbase + i*16 (wave-uniform base)
__device__ __forceinline__ void gl_lds16(const void* g, void* l) {
  __builtin_amdgcn_global_load_lds(
      (const __attribute__((address_space(1))) unsigned int*)g,
      (__attribute__((address_space(3))) unsigned int*)l, 16, 0, 0);
}

// ---------------------------------------------------------------------------
// W split: QKV (p<3) -> iv-scaled f16 2-split; proj -> iv-scaled bf16 3-split.
// ---------------------------------------------------------------------------
struct WSplitArgs {
  const float* w[4]; const float* g[4]; const float* be[4];
  const float* mu[4]; const float* va[4]; const float* bias;
};
__global__ __launch_bounds__(256) void split_w(
    WSplitArgs a, _Float16* __restrict__ wsp16, __bf16* __restrict__ wspb,
    float* __restrict__ shv) {
  const int i = blockIdx.x * 256 + threadIdx.x;   // < 589824
  const int p = i / WSZ, r = i - p * WSZ;
  const int o = r / Cn;
  const float iv = a.g[p][o] / sqrtf(a.va[p][o] + 1e-5f);
  const float wv = a.w[p][r] * iv;
  if (p < 3) {
    _Float16 h, l;
    split2h(wv, h, l);
    wsp16[(size_t)(p * 2 + 0) * WSZ + r] = h;
    wsp16[(size_t)(p * 2 + 1) * WSZ + r] = l;
  } else {
    __bf16 h, m, l;
    split3(wv, h, m, l);
    wspb[(size_t)0 * WSZ + r] = h;
    wspb[(size_t)1 * WSZ + r] = m;
    wspb[(size_t)2 * WSZ + r] = l;
  }
  if (r - o * Cn == 0) {
    float sh = a.be[p][o] - a.mu[p][o] * iv;
    if (p == 3) sh += a.bias[o] * iv;
    shv[p * Cn + o] = sh;
  }
}

// ---------------------------------------------------------------------------
// x [t,b,c,n] -> pre-split f16 planes xs[s][t][col=(b,n)][c], s=h/l.
// ---------------------------------------------------------------------------
__global__ __launch_bounds__(256) void transpose_split_x(
    const float* __restrict__ x, _Float16* __restrict__ xs) {
  __shared__ float tile[49 * 130];
  const int t = blockIdx.x, b = blockIdx.y;
  const int ct = blockIdx.z >> 2, nch = blockIdx.z & 3;
  const int c0 = ct * 128, n0 = nch * 49;
  const int tid = threadIdx.x;
  for (int idx = tid; idx < 49 * 128; idx += 256) {
    const int n = idx % 49, c = idx / 49;
    tile[n * 130 + c] = x[(size_t)t * BCNn + (size_t)b * CNn +
                          (size_t)(c0 + c) * Nn + n0 + n];
  }
  __syncthreads();
  for (int idx = tid; idx < 49 * 64; idx += 256) {
    const int cp = idx & 63, n = idx >> 6;
    const float v0 = tile[n * 130 + cp * 2];
    const float v1 = tile[n * 130 + cp * 2 + 1];
    _Float16 h0, l0, h1, l1;
    split2h(v0, h0, l0);
    split2h(v1, h1, l1);
    const size_t col = (size_t)t * NCOLS + (size_t)b * Nn + n0 + n;
    union { _Float16 f[2]; u32 u; } uh, ul;
    uh.f[0] = h0; uh.f[1] = h1;
    ul.f[0] = l0; ul.f[1] = l1;
    ((u32*)(xs + col * Cn + c0))[cp] = uh.u;
    ((u32*)(xs + (size_t)TBCNn + col * Cn + c0))[cp] = ul.u;
  }
}

// ---------------------------------------------------------------------------
// FUSED QKV GEMM + LIF(1.0) + bitpack, v2.
// 64-col x 128-o tiles -> 98*9 = 882 blocks (R2's 441 left CUs half-idle).
// Flat 48-step (t,kk) loop with double-buffered LDS and ONE barrier per step:
// step s issues global_load_lds for step s+1 into buf^1, computes step s from
// buf; __syncthreads()'s vmcnt drain is the producer wait (T3 minimum
// 2-phase). LIF membrane state stays in registers across t; epilogue packs
// spike bits via cross-quad shfl-OR.
// ---------------------------------------------------------------------------
__global__ __launch_bounds__(256, 2) void gemm_qkv_lif(
    const _Float16* __restrict__ xs,    // [2][t][col][c] f16 pre-split
    const _Float16* __restrict__ wsp16, // [3][2][o][c] iv-scaled f16 2-split
    const float* __restrict__ shv,      // [4][o]
    u32* __restrict__ bq, u32* __restrict__ bk, u32* __restrict__ bv)
{
  __shared__ _Float16 Asw[2][2][128][32];   // [buf][split][o][k]  16KB/buf
  __shared__ _Float16 Bsw[2][2][64][32];    // [buf][split][col][k] 8KB/buf
  // bijective chunked XCD swizzle over 882 wgs (q=110, r=2): a colt's 9
  // (p,mt) variants stay consecutive on one XCD -> B-panel L2 reuse.
  const int orig = blockIdx.x;
  const int xcd = orig & 7, i8 = orig >> 3;
  const int wgid = xcd * 110 + (xcd < 2 ? xcd : 2) + i8;
  const int colt = wgid / 9, v = wgid - colt * 9;
  const int col0 = colt * 64;
  const int p = v / 3, mt = v - p * 3;
  const int o0 = mt * 128;
  const int tid = threadIdx.x, lane = tid & 63, wid = tid >> 6;
  const int wm = wid >> 1, wn = wid & 1;
  const int quad = lane >> 4, nl = lane & 15;
  u32* __restrict__ bits = (p == 0) ? bq : (p == 1) ? bk : bv;

  // per-lane staging source offsets (pre-swizzled so linear LDS dest +
  // XOR-swizzled fragment reads are conflict-free; rule #21).
  u32 aOff[4], bOff[2];
#pragma unroll
  for (int i = 0; i < 4; ++i) {
    const int c = i * 256 + wid * 64 + lane;     // A chunk 0..1023
    const int s = c >> 9, row = (c >> 2) & 127, kb = c & 3;
    const int kbs = kb ^ ((row >> 1) & 3);
    aOff[i] = (u32)((((p * 2 + s) * WSZ) + (o0 + row) * Cn + kbs * 8) * 2);
  }
#pragma unroll
  for (int i = 0; i < 2; ++i) {
    const int c = i * 256 + wid * 64 + lane;     // B chunk 0..511
    const int s = c >> 8, rem = c & 255, row = rem >> 2, kb = rem & 3;
    const int kbs = kb ^ ((row >> 1) & 3);
    bOff[i] = (u32)(((size_t)s * TBCNn + (size_t)(col0 + row) * Cn + kbs * 8) * 2);
  }
  const char* wB = (const char*)wsp16;
  const char* xB = (const char*)xs;
  char* aD0 = (char*)&Asw[0][0][0][0] + wid * 1024;
  char* bD0 = (char*)&Bsw[0][0][0][0] + wid * 1024;

#define STAGE_QKV(s_, buf_) do {                                          \
    const int t_ = (s_) / 12, kk_ = (s_) - t_ * 12;                       \
    const u32 ak_ = (u32)(kk_ * 64);                                      \
    const u32 bk_ = ak_ + (u32)t_ * (u32)(NCOLS * Cn * 2);                \
    _Pragma("unroll") for (int i_ = 0; i_ < 4; ++i_)                      \
      gl_lds16(wB + aOff[i_] + ak_, aD0 + (buf_) * 16384 + i_ * 4096);    \
    _Pragma("unroll") for (int i_ = 0; i_ < 2; ++i_)                      \
      gl_lds16(xB + bOff[i_] + bk_, bD0 + (buf_) * 8192 + i_ * 4096);     \
  } while (0)

  // BN shift, t-invariant
  f32x4 sh_[4];
#pragma unroll
  for (int mi = 0; mi < 4; ++mi)
    sh_[mi] = *(const f32x4*)&shv[p * Cn + o0 + wm * 64 + mi * 16 + quad * 4];

  f32x4 acc[4][2];
  f32x4 vst[4][2] = {};   // LIF membrane, persists across t

  STAGE_QKV(0, 0);
  __syncthreads();        // drains vmcnt -> buf0 ready

#pragma unroll 2
  for (int s = 0; s < 48; ++s) {
    const int kk = s % 12;
    const int buf = s & 1;
    if (s < 47) STAGE_QKV(s + 1, buf ^ 1);   // prefetch next step
    if (kk == 0) {
#pragma unroll
      for (int mi = 0; mi < 4; ++mi)
#pragma unroll
        for (int ni = 0; ni < 2; ++ni) acc[mi][ni] = f32x4{0.f, 0.f, 0.f, 0.f};
    }
    f16x8 bfr[2][2];
#pragma unroll
    for (int i = 0; i < 2; ++i) {
      const int rb = wn * 32 + i * 16 + nl;
      const int kb2 = (quad ^ ((rb >> 1) & 3)) * 8;
#pragma unroll
      for (int sp_ = 0; sp_ < 2; ++sp_)
        bfr[sp_][i] = *(const f16x8*)&Bsw[buf][sp_][rb][kb2];
    }
#pragma unroll
    for (int mi = 0; mi < 4; ++mi) {
      const int ra = wm * 64 + mi * 16 + nl;
      const int ka = (quad ^ ((ra >> 1) & 3)) * 8;
      const f16x8 a0 = *(const f16x8*)&Asw[buf][0][ra][ka];
      const f16x8 a1 = *(const f16x8*)&Asw[buf][1][ra][ka];
#pragma unroll
      for (int ni = 0; ni < 2; ++ni) {
        f32x4 c = acc[mi][ni];
        c = __builtin_amdgcn_mfma_f32_16x16x32_f16(a0, bfr[0][ni], c, 0, 0, 0);
        c = __builtin_amdgcn_mfma_f32_16x16x32_f16(a0, bfr[1][ni], c, 0, 0, 0);
        c = __builtin_amdgcn_mfma_f32_16x16x32_f16(a1, bfr[0][ni], c, 0, 0, 0);
        acc[mi][ni] = c;
      }
    }
    __syncthreads();   // one barrier/step: syncs LDS reads + drains prefetch
    if (kk == 11) {
      const int t = s / 12;
      // epilogue: LIF + bitpack (register-only; overlaps issued prefetch)
#pragma unroll
      for (int ni = 0; ni < 2; ++ni) {
        u32 w0 = 0, w1 = 0;
#pragma unroll
        for (int mi = 0; mi < 4; ++mi) {
#pragma unroll
          for (int r = 0; r < 4; ++r) {
            const float y = acc[mi][ni][r] + sh_[mi][r];
            const float vv = vst[mi][ni][r];
            const float nv = vv + (y - vv) * 0.5f;
            const bool sk = nv >= 1.0f;
            vst[mi][ni][r] = sk ? 0.f : nv;
            const u32 b1 = sk ? 1u : 0u;
            const int pos = ((mi & 1) << 4) + (quad << 2) + r;
            if (mi < 2) w0 |= b1 << pos; else w1 |= b1 << pos;
          }
        }
        // OR across the 4 quads (lanes nl, nl+16, nl+32, nl+48)
        w0 |= __shfl_xor(w0, 16); w0 |= __shfl_xor(w0, 32);
        w1 |= __shfl_xor(w1, 16); w1 |= __shfl_xor(w1, 32);
        if (quad == 0) {
          const int col = col0 + wn * 32 + ni * 16 + nl;
          const int bb = col / Nn, nn = col - bb * Nn;
          u32* bp = bits + (size_t)t * BHNn +
                    ((size_t)bb * Hn + (mt * 4 + wm * 2)) * Nn + nn;
          bp[0] = w0;       // h = mt*4 + wm*2
          bp[Nn] = w1;      // h = mt*4 + wm*2 + 1
        }
      }
    }
  }
#undef STAGE_QKV
}

// ---------------------------------------------------------------------------
// FUSED MFMA attention + LIF(0.5). One block per (b,h) = 384 blocks; t-loop
// inside so LIF state stays in registers; emits bf16 spikes directly to sp.
// y = A.U + diag, A[n,m]=popc(q&k) (exact bf16 int), U[m,d]=p_m*v[m,d]
// (exact fp32, 3-split bf16), diag adds a(n,n)*(1-p_n)*v[n,d].
// ---------------------------------------------------------------------------
#define ASTR 40
__global__ __launch_bounds__(256) void attn_lif(
    const u32* __restrict__ qb, const u32* __restrict__ kb,
    const u32* __restrict__ vb, const float* __restrict__ policy,
    __bf16* __restrict__ sp) {
  __shared__ u32 qs[208], ks[224], vs_[224];
  __shared__ float ps[224];
  __shared__ __bf16 psp[3][224];
  __shared__ __bf16 Al[208 * ASTR];
  __shared__ __bf16 Ul[3][32 * ASTR];
  const int bh = blockIdx.x;           // b*H + h
  const int bN = bh / Hn;
  const int h = bh - bN * Hn;
  const int tid = threadIdx.x;
  const int lane = tid & 63, wid = tid >> 6;
  const int quad = lane >> 4, nl = lane & 15;

  float vst[4][2][4] = {};   // LIF(0.5) membrane, persistent across t

  for (int t = 0; t < Tn; ++t) {
    const int tb = t * Bn + bN;
    const int gid = tb * Hn + h;
    if (t) __syncthreads();   // prior epilogue reads qs/vs_/ps done
    // stage bits + policy (zero-padded)
    for (int i = tid; i < 224; i += 256) {
      const bool in = i < Nn;
      if (i < 208) qs[i] = in ? qb[(size_t)gid * Nn + i] : 0u;
      ks[i] = in ? kb[(size_t)gid * Nn + i] : 0u;
      vs_[i] = in ? vb[(size_t)gid * Nn + i] : 0u;
      const float p = in ? policy[(size_t)tb * Nn + i] : 0.f;
      ps[i] = p;
      __bf16 hh, mm, ll;
      split3(p, hh, mm, ll);
      psp[0][i] = hh; psp[1][i] = mm; psp[2][i] = ll;
    }
    __syncthreads();

    f32x4 acc[4][2] = {};

    for (int slab = 0; slab < 7; ++slab) {
      const int m0 = slab * 32;
      if (tid < 208) {
        const u32 qn = qs[tid];
        __bf16 a32[32];
#pragma unroll
        for (int mk = 0; mk < 32; ++mk)
          a32[mk] = (__bf16)(float)__popc(qn & ks[m0 + mk]);
#pragma unroll
        for (int g = 0; g < 4; ++g)
          *(bf16x8*)&Al[tid * ASTR + g * 8] = *(bf16x8*)&a32[g * 8];
      }
      {
        const int dp = tid >> 3, mkg = (tid & 7) * 4;
        __bf16 u4[3][4];
#pragma unroll
        for (int j = 0; j < 4; ++j) {
          const int m = m0 + mkg + j;
          const bool bit = (vs_[m] >> dp) & 1u;
#pragma unroll
          for (int s = 0; s < 3; ++s)
            u4[s][j] = bit ? psp[s][m] : (__bf16)0.f;
        }
#pragma unroll
        for (int s = 0; s < 3; ++s)
          *(bf16x4v*)&Ul[s][dp * ASTR + mkg] = *(bf16x4v*)u4[s];
      }
      __syncthreads();
      bf16x8 bfr[3][2];
#pragma unroll
      for (int s = 0; s < 3; ++s)
#pragma unroll
        for (int nt = 0; nt < 2; ++nt)
          bfr[s][nt] = *(const bf16x8*)&Ul[s][(nt * 16 + nl) * ASTR + quad * 8];
#pragma unroll
      for (int mi = 0; mi < 4; ++mi) {
        const int mt2 = wid + mi * 4;
        if (mt2 < 13) {
          const bf16x8 af = *(const bf16x8*)&Al[(mt2 * 16 + nl) * ASTR + quad * 8];
#pragma unroll
          for (int nt = 0; nt < 2; ++nt) {
            f32x4 c = acc[mi][nt];
            c = __builtin_amdgcn_mfma_f32_16x16x32_bf16(af, bfr[0][nt], c, 0, 0, 0);
            c = __builtin_amdgcn_mfma_f32_16x16x32_bf16(af, bfr[1][nt], c, 0, 0, 0);
            c = __builtin_amdgcn_mfma_f32_16x16x32_bf16(af, bfr[2][nt], c, 0, 0, 0);
            acc[mi][nt] = c;
          }
        }
      }
      __syncthreads();
    }
    // epilogue: diag + *0.25, fused LIF(0.5), bf16 spike store
#pragma unroll
    for (int mi = 0; mi < 4; ++mi) {
      const int mt2 = wid + mi * 4;
      if (mt2 >= 13) continue;
#pragma unroll
      for (int r = 0; r < 4; ++r) {
        const int n = mt2 * 16 + quad * 4 + r;
        if (n >= Nn) continue;
        const float ann = (float)__popc(qs[n] & ks[n]);
        const float wd = ann * (1.0f - ps[n]);
        const u32 vn = vs_[n];
        __bf16* op = sp + (size_t)t * BCNn + ((size_t)bN * Nn + n) * Cn + h * 32;
#pragma unroll
        for (int nt = 0; nt < 2; ++nt) {
          const int d = nt * 16 + nl;
          const float bit = (float)((vn >> d) & 1u);
          const float y = (acc[mi][nt][r] + wd * bit) * 0.25f;
          const float vv = vst[mi][nt][r];
          const float nv = vv + (y - vv) * 0.5f;
          const bool s = nv >= 0.5f;
          vst[mi][nt][r] = s ? 0.f : nv;
          op[d] = (__bf16)(s ? 1.0f : 0.0f);
        }
      }
    }
  }
}

// ---------------------------------------------------------------------------
// proj GEMM: 3-split iv-scaled bf16 W x binary bf16 spikes (exact).
// ---------------------------------------------------------------------------
__global__ __launch_bounds__(256, 3) void gemm_proj_mfma(
    const __bf16* __restrict__ sp, const __bf16* __restrict__ wspb,
    const float* __restrict__ shv, float* __restrict__ z)
{
  __shared__ __bf16 Asw[3][128][32];
  __shared__ __bf16 Bsw[128][32];
  const int bid = blockIdx.x;
  const int xcd = bid & 7, slot = bid >> 3;      // slot 0..74
  const int gl = slot / 3, mt = slot - gl * 3;
  const int group = xcd * 25 + gl;
  if (group >= 196) return;
  const int colt = group % 49, t = group / 49;
  const int col0 = colt * 128, o0 = mt * 128;
  const int tid = threadIdx.x, lane = tid & 63, wid = tid >> 6;
  const int wm = wid >> 1, wn = wid & 1;
  const int quad = lane >> 4, nl = lane & 15;
  const __bf16* Bg = sp + ((size_t)t * NCOLS + col0) * Cn;

  f32x4 acc[4][4] = {};
  bf16x8 aval[6], bval[2];
#pragma unroll
  for (int i = 0; i < 6; ++i) {
    const int u = tid + i * 256, s = u >> 9, rem = u & 511;
    const int row = rem >> 2, kb = rem & 3;
    aval[i] = *(const bf16x8*)(wspb + (size_t)s * WSZ + (size_t)(o0 + row) * Cn + kb * 8);
  }
#pragma unroll
  for (int i = 0; i < 2; ++i) {
    const int u = tid + i * 256, row = u >> 2, kb = u & 3;
    bval[i] = *(const bf16x8*)(Bg + (size_t)row * Cn + kb * 8);
  }

  for (int kk = 0; kk < 12; ++kk) {
    __syncthreads();
#pragma unroll
    for (int i = 0; i < 6; ++i) {
      const int u = tid + i * 256, s = u >> 9, rem = u & 511;
      const int row = rem >> 2, kb = rem & 3;
      const int kbp = kb ^ ((row >> 1) & 3);
      *(bf16x8*)&Asw[s][row][kbp * 8] = aval[i];
    }
#pragma unroll
    for (int i = 0; i < 2; ++i) {
      const int u = tid + i * 256, row = u >> 2, kb = u & 3;
      const int kbp = kb ^ ((row >> 1) & 3);
      *(bf16x8*)&Bsw[row][kbp * 8] = bval[i];
    }
    __syncthreads();
    if (kk < 11) {
      const int k0n = (kk + 1) * 32;
#pragma unroll
      for (int i = 0; i < 6; ++i) {
        const int u = tid + i * 256, s = u >> 9, rem = u & 511;
        const int row = rem >> 2, kb = rem & 3;
        aval[i] = *(const bf16x8*)(wspb + (size_t)s * WSZ +
                                   (size_t)(o0 + row) * Cn + k0n + kb * 8);
      }
#pragma unroll
      for (int i = 0; i < 2; ++i) {
        const int u = tid + i * 256, row = u >> 2, kb = u & 3;
        bval[i] = *(const bf16x8*)(Bg + (size_t)row * Cn + k0n + kb * 8);
      }
    }
    bf16x8 af[3][4], bfr[4];
#pragma unroll
    for (int i = 0; i < 4; ++i) {
      const int ra = wm * 64 + i * 16 + nl;
      const int rb = wn * 64 + i * 16 + nl;
      const int ka = (quad ^ ((ra >> 1) & 3)) * 8;
      const int kb2 = (quad ^ ((rb >> 1) & 3)) * 8;
      bfr[i] = *(const bf16x8*)&Bsw[rb][kb2];
#pragma unroll
      for (int s = 0; s < 3; ++s)
        af[s][i] = *(const bf16x8*)&Asw[s][ra][ka];
    }
#pragma unroll
    for (int mi = 0; mi < 4; ++mi)
#pragma unroll
      for (int ni = 0; ni < 4; ++ni) {
        f32x4 c = acc[mi][ni];
        c = __builtin_amdgcn_mfma_f32_16x16x32_bf16(af[0][mi], bfr[ni], c, 0, 0, 0);
        c = __builtin_amdgcn_mfma_f32_16x16x32_bf16(af[1][mi], bfr[ni], c, 0, 0, 0);
        c = __builtin_amdgcn_mfma_f32_16x16x32_bf16(af[2][mi], bfr[ni], c, 0, 0, 0);
        acc[mi][ni] = c;
      }
  }
#pragma unroll
  for (int mi = 0; mi < 4; ++mi) {
    const int ob = o0 + wm * 64 + mi * 16 + quad * 4;
    const f32x4 sh4 = *(const f32x4*)&shv[3 * Cn + ob];
#pragma unroll
    for (int ni = 0; ni < 4; ++ni) {
      const int col = col0 + wn * 64 + ni * 16 + nl;
      const int b = col / Nn, nn = col - b * Nn;
      float* zp = z + (size_t)t * BCNn + (size_t)b * CNn + nn;
#pragma unroll
      for (int r = 0; r < 4; ++r)
        zp[(size_t)(ob + r) * Nn] = acc[mi][ni][r] + sh4[r];
    }
  }
}

// final LIF(1.0): z [t,b,o,n] fp32 -> out binary fp32
__global__ __launch_bounds__(256) void lif_out_v4(
    const float* __restrict__ z, float* __restrict__ out) {
  const size_t i4 = ((size_t)blockIdx.x * 256 + threadIdx.x) * 4;
  f32x4 v = {0.f, 0.f, 0.f, 0.f};
#pragma unroll
  for (int t = 0; t < Tn; ++t) {
    f32x4 x = *(const f32x4*)(z + (size_t)t * BCNn + i4);
    f32x4 o4;
#pragma unroll
    for (int r = 0; r < 4; ++r) {
      const float nv = v[r] + (x[r] - v[r]) * 0.5f;
      const bool s = nv >= 1.0f;
      o4[r] = s ? 1.0f : 0.0f;
      v[r] = s ? 0.f : nv;
    }
    *(f32x4*)(out + (size_t)t * BCNn + i4) = o4;
  }
}

// ===========================================================================
extern "C" void kernel_launch(void* const* d_in, const int* in_sizes, int n_in,
                              void* d_out, int out_size, void* d_ws, size_t ws_size,
                              hipStream_t stream) {
  const float* x      = (const float*)d_in[0];
  const float* policy = (const float*)d_in[1];
  const float* qw = (const float*)d_in[2];
  const float* qg = (const float*)d_in[3];
  const float* qb_ = (const float*)d_in[4];
  const float* qm = (const float*)d_in[5];
  const float* qv = (const float*)d_in[6];
  const float* kw = (const float*)d_in[7];
  const float* kg = (const float*)d_in[8];
  const float* kbe = (const float*)d_in[9];
  const float* km = (const float*)d_in[10];
  const float* kv = (const float*)d_in[11];
  const float* vw = (const float*)d_in[12];
  const float* vg = (const float*)d_in[13];
  const float* vbe = (const float*)d_in[14];
  const float* vm = (const float*)d_in[15];
  const float* vv = (const float*)d_in[16];
  const float* pw = (const float*)d_in[17];
  const float* pg = (const float*)d_in[18];
  const float* pbe = (const float*)d_in[19];
  const float* pm = (const float*)d_in[20];
  const float* pv = (const float*)d_in[21];
  const float* pbias = (const float*)d_in[22];
  float* out = (float*)d_out;

  char* base = (char*)d_ws;
  _Float16* xs   = (_Float16*)base;                               // 38,535,168
  _Float16* wsp16 = (_Float16*)(base + (size_t)TBCNn * 4);        //  1,769,472
  __bf16* wspb   = (__bf16*)((char*)wsp16 + (size_t)6 * WSZ * 2); //    884,736
  float* shv     = (float*)((char*)wspb + (size_t)3 * WSZ * 2);   //      6,144
  u32* bq        = (u32*)((char*)shv + 4 * Cn * 4);               //  1,204,224 x3
  u32* bk = bq + PBITS;
  u32* bv = bk + PBITS;
  __bf16* sp     = (__bf16*)(bv + PBITS);                         // 19,267,584
  float* z       = (float*)((char*)sp + (size_t)TBCNn * 2);       // 38,535,168

  WSplitArgs wa;
  wa.w[0] = qw; wa.g[0] = qg; wa.be[0] = qb_; wa.mu[0] = qm; wa.va[0] = qv;
  wa.w[1] = kw; wa.g[1] = kg; wa.be[1] = kbe; wa.mu[1] = km; wa.va[1] = kv;
  wa.w[2] = vw; wa.g[2] = vg; wa.be[2] = vbe; wa.mu[2] = vm; wa.va[2] = vv;
  wa.w[3] = pw; wa.g[3] = pg; wa.be[3] = pbe; wa.mu[3] = pm; wa.va[3] = pv;
  wa.bias = pbias;
  split_w<<<2304, 256, 0, stream>>>(wa, wsp16, wspb, shv);
  transpose_split_x<<<dim3(4, 32, 12), 256, 0, stream>>>(x, xs);

  gemm_qkv_lif<<<882, 256, 0, stream>>>(xs, wsp16, shv, bq, bk, bv);
  attn_lif<<<Bn * Hn, 256, 0, stream>>>(bq, bk, bv, policy, sp);
  gemm_proj_mfma<<<600, 256, 0, stream>>>(sp, wspb, shv, z);
  lif_out_v4<<<BCNn / 1024, 256, 0, stream>>>(z, out);
}

// Round 4
// 317.649 us; speedup vs baseline: 1.1489x; 1.0136x over previous
//
#include <hip/hip_runtime.h>

typedef unsigned int u32;
typedef __bf16 bf16x8 __attribute__((ext_vector_type(8)));
typedef __bf16 bf16x4v __attribute__((ext_vector_type(4)));
typedef _Float16 f16x8 __attribute__((ext_vector_type(8)));
typedef float f32x4 __attribute__((ext_vector_type(4)));

#define Tn 4
#define Bn 32
#define Cn 384
#define Nn 196
#define Hn 12
#define CNn (Cn*Nn)         // 75264
#define BCNn (Bn*CNn)       // 2408448
#define BHNn (Bn*Hn*Nn)     // 75264
#define PBITS (Tn*BHNn)     // 301056
#define TBCNn (Tn*BCNn)     // 9633792
#define NCOLS 6272          // B*N
#define WSZ 147456          // 384*384

// fp32 -> 3-way bf16 split (residual ~2^-24 rel)
__device__ __forceinline__ void split3(float v, __bf16& h, __bf16& m, __bf16& l) {
  h = (__bf16)v;  float r = v - (float)h;
  m = (__bf16)r;  float r2 = r - (float)m;
  l = (__bf16)r2;
}
// fp32 -> 2-way f16 split (residual ~2^-22 rel)
__device__ __forceinline__ void split2h(float v, _Float16& h, _Float16& l) {
  h = (_Float16)v;  l = (_Float16)(v - (float)h);
}

// direct global->LDS 16B copy: lane i lands at ldsbase + i*16 (wave-uniform base)
__device__ __forceinline__ void gl_lds16(const void* g, void* l) {
  __builtin_amdgcn_global_load_lds(
      (const __attribute__((address_space(1))) unsigned int*)g,
      (__attribute__((address_space(3))) unsigned int*)l, 16, 0, 0);
}

// ---------------------------------------------------------------------------
// W split: QKV (p<3) -> iv-scaled f16 2-split; proj -> iv-scaled bf16 3-split.
// ---------------------------------------------------------------------------
struct WSplitArgs {
  const float* w[4]; const float* g[4]; const float* be[4];
  const float* mu[4]; const float* va[4]; const float* bias;
};
__global__ __launch_bounds__(256) void split_w(
    WSplitArgs a, _Float16* __restrict__ wsp16, __bf16* __restrict__ wspb,
    float* __restrict__ shv) {
  const int i = blockIdx.x * 256 + threadIdx.x;   // < 589824
  const int p = i / WSZ, r = i - p * WSZ;
  const int o = r / Cn;
  const float iv = a.g[p][o] / sqrtf(a.va[p][o] + 1e-5f);
  const float wv = a.w[p][r] * iv;
  if (p < 3) {
    _Float16 h, l;
    split2h(wv, h, l);
    wsp16[(size_t)(p * 2 + 0) * WSZ + r] = h;
    wsp16[(size_t)(p * 2 + 1) * WSZ + r] = l;
  } else {
    __bf16 h, m, l;
    split3(wv, h, m, l);
    wspb[(size_t)0 * WSZ + r] = h;
    wspb[(size_t)1 * WSZ + r] = m;
    wspb[(size_t)2 * WSZ + r] = l;
  }
  if (r - o * Cn == 0) {
    float sh = a.be[p][o] - a.mu[p][o] * iv;
    if (p == 3) sh += a.bias[o] * iv;
    shv[p * Cn + o] = sh;
  }
}

// ---------------------------------------------------------------------------
// x [t,b,c,n] -> pre-split f16 planes xs[s][t][col=(b,n)][c], s=h/l.
// ---------------------------------------------------------------------------
__global__ __launch_bounds__(256) void transpose_split_x(
    const float* __restrict__ x, _Float16* __restrict__ xs) {
  __shared__ float tile[49 * 130];
  const int t = blockIdx.x, b = blockIdx.y;
  const int ct = blockIdx.z >> 2, nch = blockIdx.z & 3;
  const int c0 = ct * 128, n0 = nch * 49;
  const int tid = threadIdx.x;
  for (int idx = tid; idx < 49 * 128; idx += 256) {
    const int n = idx % 49, c = idx / 49;
    tile[n * 130 + c] = x[(size_t)t * BCNn + (size_t)b * CNn +
                          (size_t)(c0 + c) * Nn + n0 + n];
  }
  __syncthreads();
  for (int idx = tid; idx < 49 * 64; idx += 256) {
    const int cp = idx & 63, n = idx >> 6;
    const float v0 = tile[n * 130 + cp * 2];
    const float v1 = tile[n * 130 + cp * 2 + 1];
    _Float16 h0, l0, h1, l1;
    split2h(v0, h0, l0);
    split2h(v1, h1, l1);
    const size_t col = (size_t)t * NCOLS + (size_t)b * Nn + n0 + n;
    union { _Float16 f[2]; u32 u; } uh, ul;
    uh.f[0] = h0; uh.f[1] = h1;
    ul.f[0] = l0; ul.f[1] = l1;
    ((u32*)(xs + col * Cn + c0))[cp] = uh.u;
    ((u32*)(xs + (size_t)TBCNn + col * Cn + c0))[cp] = ul.u;
  }
}

// ---------------------------------------------------------------------------
// FUSED QKV GEMM + LIF(1.0) + bitpack, v3: counted-vmcnt 2-deep pipeline.
// 64-col x 128-o tiles -> 882 blocks. Flat 48-step (t,kk) loop, THREE LDS
// buffers: step s issues global_load_lds for step s+2; at step top each wave
// waits vmcnt(6) (own loads for s done; s+1's 6 stay in flight), then RAW
// s_barrier (no vmcnt(0) drain -- T3+T4; __syncthreads would drain the
// pipe and serialize load latency into every step, the R3 bottleneck).
// LIF membrane state in registers across t; epilogue packs bits via shfl-OR.
// ---------------------------------------------------------------------------
__global__ __launch_bounds__(256, 2) void gemm_qkv_lif(
    const _Float16* __restrict__ xs,    // [2][t][col][c] f16 pre-split
    const _Float16* __restrict__ wsp16, // [3][2][o][c] iv-scaled f16 2-split
    const float* __restrict__ shv,      // [4][o]
    u32* __restrict__ bq, u32* __restrict__ bk, u32* __restrict__ bv)
{
  __shared__ _Float16 Asw[3][2][128][32];   // [buf][split][o][k]   16KB/buf
  __shared__ _Float16 Bsw[3][2][64][32];    // [buf][split][col][k]  8KB/buf
  // bijective chunked XCD swizzle over 882 wgs (q=110, r=2): a colt's 9
  // (p,mt) variants stay consecutive on one XCD -> B-panel L2 reuse.
  const int orig = blockIdx.x;
  const int xcd = orig & 7, i8 = orig >> 3;
  const int wgid = xcd * 110 + (xcd < 2 ? xcd : 2) + i8;
  const int colt = wgid / 9, v = wgid - colt * 9;
  const int col0 = colt * 64;
  const int p = v / 3, mt = v - p * 3;
  const int o0 = mt * 128;
  const int tid = threadIdx.x, lane = tid & 63, wid = tid >> 6;
  const int wm = wid >> 1, wn = wid & 1;
  const int quad = lane >> 4, nl = lane & 15;
  u32* __restrict__ bits = (p == 0) ? bq : (p == 1) ? bk : bv;

  // per-lane staging source offsets (pre-swizzled so linear LDS dest +
  // XOR-swizzled fragment reads are conflict-free; rule #21).
  u32 aOff[4], bOff[2];
#pragma unroll
  for (int i = 0; i < 4; ++i) {
    const int c = i * 256 + wid * 64 + lane;     // A chunk 0..1023
    const int s = c >> 9, row = (c >> 2) & 127, kb = c & 3;
    const int kbs = kb ^ ((row >> 1) & 3);
    aOff[i] = (u32)((((p * 2 + s) * WSZ) + (o0 + row) * Cn + kbs * 8) * 2);
  }
#pragma unroll
  for (int i = 0; i < 2; ++i) {
    const int c = i * 256 + wid * 64 + lane;     // B chunk 0..511
    const int s = c >> 8, rem = c & 255, row = rem >> 2, kb = rem & 3;
    const int kbs = kb ^ ((row >> 1) & 3);
    bOff[i] = (u32)(((size_t)s * TBCNn + (size_t)(col0 + row) * Cn + kbs * 8) * 2);
  }
  const char* wB = (const char*)wsp16;
  const char* xB = (const char*)xs;
  char* aD0 = (char*)&Asw[0][0][0][0] + wid * 1024;
  char* bD0 = (char*)&Bsw[0][0][0][0] + wid * 1024;

#define STAGE_QKV(s_, buf_) do {                                          \
    const int t_ = (s_) / 12, kk_ = (s_) - t_ * 12;                       \
    const u32 ak_ = (u32)(kk_ * 64);                                      \
    const u32 bk_ = ak_ + (u32)t_ * (u32)(NCOLS * Cn * 2);                \
    _Pragma("unroll") for (int i_ = 0; i_ < 4; ++i_)                      \
      gl_lds16(wB + aOff[i_] + ak_, aD0 + (buf_) * 16384 + i_ * 4096);    \
    _Pragma("unroll") for (int i_ = 0; i_ < 2; ++i_)                      \
      gl_lds16(xB + bOff[i_] + bk_, bD0 + (buf_) * 8192 + i_ * 4096);     \
  } while (0)

  // BN shift, t-invariant
  f32x4 sh_[4];
#pragma unroll
  for (int mi = 0; mi < 4; ++mi)
    sh_[mi] = *(const f32x4*)&shv[p * Cn + o0 + wm * 64 + mi * 16 + quad * 4];

  f32x4 acc[4][2];
  f32x4 vst[4][2] = {};   // LIF membrane, persists across t

  STAGE_QKV(0, 0);
  STAGE_QKV(1, 1);

#pragma unroll 1
  for (int s = 0; s < 48; ++s) {
    const int kk = s % 12;
    const int buf = s % 3;
    // wait for OWN loads of step s (6 remain in flight for step s+1),
    // then raw barrier: all waves' step-s loads have landed in LDS.
    if (s < 47) asm volatile("s_waitcnt vmcnt(6)" ::: "memory");
    else        asm volatile("s_waitcnt vmcnt(0)" ::: "memory");
    __builtin_amdgcn_s_barrier();
    __builtin_amdgcn_sched_barrier(0);
    // buf[(s+2)%3] == buf[(s-1)%3]: all waves finished reading it (barrier)
    if (s + 2 < 48) STAGE_QKV(s + 2, (s + 2) % 3);
    if (kk == 0) {
#pragma unroll
      for (int mi = 0; mi < 4; ++mi)
#pragma unroll
        for (int ni = 0; ni < 2; ++ni) acc[mi][ni] = f32x4{0.f, 0.f, 0.f, 0.f};
    }
    f16x8 bfr[2][2];
#pragma unroll
    for (int i = 0; i < 2; ++i) {
      const int rb = wn * 32 + i * 16 + nl;
      const int kb2 = (quad ^ ((rb >> 1) & 3)) * 8;
#pragma unroll
      for (int sp_ = 0; sp_ < 2; ++sp_)
        bfr[sp_][i] = *(const f16x8*)&Bsw[buf][sp_][rb][kb2];
    }
#pragma unroll
    for (int mi = 0; mi < 4; ++mi) {
      const int ra = wm * 64 + mi * 16 + nl;
      const int ka = (quad ^ ((ra >> 1) & 3)) * 8;
      const f16x8 a0 = *(const f16x8*)&Asw[buf][0][ra][ka];
      const f16x8 a1 = *(const f16x8*)&Asw[buf][1][ra][ka];
#pragma unroll
      for (int ni = 0; ni < 2; ++ni) {
        f32x4 c = acc[mi][ni];
        c = __builtin_amdgcn_mfma_f32_16x16x32_f16(a0, bfr[0][ni], c, 0, 0, 0);
        c = __builtin_amdgcn_mfma_f32_16x16x32_f16(a0, bfr[1][ni], c, 0, 0, 0);
        c = __builtin_amdgcn_mfma_f32_16x16x32_f16(a1, bfr[0][ni], c, 0, 0, 0);
        acc[mi][ni] = c;
      }
    }
    if (kk == 11) {
      const int t = s / 12;
      // epilogue: LIF + bitpack (register-only; overlaps in-flight prefetch)
#pragma unroll
      for (int ni = 0; ni < 2; ++ni) {
        u32 w0 = 0, w1 = 0;
#pragma unroll
        for (int mi = 0; mi < 4; ++mi) {
#pragma unroll
          for (int r = 0; r < 4; ++r) {
            const float y = acc[mi][ni][r] + sh_[mi][r];
            const float vv = vst[mi][ni][r];
            const float nv = vv + (y - vv) * 0.5f;
            const bool sk = nv >= 1.0f;
            vst[mi][ni][r] = sk ? 0.f : nv;
            const u32 b1 = sk ? 1u : 0u;
            const int pos = ((mi & 1) << 4) + (quad << 2) + r;
            if (mi < 2) w0 |= b1 << pos; else w1 |= b1 << pos;
          }
        }
        // OR across the 4 quads (lanes nl, nl+16, nl+32, nl+48)
        w0 |= __shfl_xor(w0, 16); w0 |= __shfl_xor(w0, 32);
        w1 |= __shfl_xor(w1, 16); w1 |= __shfl_xor(w1, 32);
        if (quad == 0) {
          const int col = col0 + wn * 32 + ni * 16 + nl;
          const int bb = col / Nn, nn = col - bb * Nn;
          u32* bp = bits + (size_t)t * BHNn +
                    ((size_t)bb * Hn + (mt * 4 + wm * 2)) * Nn + nn;
          bp[0] = w0;       // h = mt*4 + wm*2
          bp[Nn] = w1;      // h = mt*4 + wm*2 + 1
        }
      }
    }
  }
#undef STAGE_QKV
}

// ---------------------------------------------------------------------------
// FUSED MFMA attention + LIF(0.5). One block per (b,h) = 384 blocks; t-loop
// inside so LIF state stays in registers; emits bf16 spikes directly to sp.
// y = A.U + diag, A[n,m]=popc(q&k) (exact bf16 int), U[m,d]=p_m*v[m,d]
// (exact fp32, 3-split bf16), diag adds a(n,n)*(1-p_n)*v[n,d].
// ---------------------------------------------------------------------------
#define ASTR 40
__global__ __launch_bounds__(256) void attn_lif(
    const u32* __restrict__ qb, const u32* __restrict__ kb,
    const u32* __restrict__ vb, const float* __restrict__ policy,
    __bf16* __restrict__ sp) {
  __shared__ u32 qs[208], ks[224], vs_[224];
  __shared__ float ps[224];
  __shared__ __bf16 psp[3][224];
  __shared__ __bf16 Al[208 * ASTR];
  __shared__ __bf16 Ul[3][32 * ASTR];
  const int bh = blockIdx.x;           // b*H + h
  const int bN = bh / Hn;
  const int h = bh - bN * Hn;
  const int tid = threadIdx.x;
  const int lane = tid & 63, wid = tid >> 6;
  const int quad = lane >> 4, nl = lane & 15;

  float vst[4][2][4] = {};   // LIF(0.5) membrane, persistent across t

  for (int t = 0; t < Tn; ++t) {
    const int tb = t * Bn + bN;
    const int gid = tb * Hn + h;
    if (t) __syncthreads();   // prior epilogue reads qs/vs_/ps done
    // stage bits + policy (zero-padded)
    for (int i = tid; i < 224; i += 256) {
      const bool in = i < Nn;
      if (i < 208) qs[i] = in ? qb[(size_t)gid * Nn + i] : 0u;
      ks[i] = in ? kb[(size_t)gid * Nn + i] : 0u;
      vs_[i] = in ? vb[(size_t)gid * Nn + i] : 0u;
      const float p = in ? policy[(size_t)tb * Nn + i] : 0.f;
      ps[i] = p;
      __bf16 hh, mm, ll;
      split3(p, hh, mm, ll);
      psp[0][i] = hh; psp[1][i] = mm; psp[2][i] = ll;
    }
    __syncthreads();

    f32x4 acc[4][2] = {};

    for (int slab = 0; slab < 7; ++slab) {
      const int m0 = slab * 32;
      if (tid < 208) {
        const u32 qn = qs[tid];
        __bf16 a32[32];
#pragma unroll
        for (int mk = 0; mk < 32; ++mk)
          a32[mk] = (__bf16)(float)__popc(qn & ks[m0 + mk]);
#pragma unroll
        for (int g = 0; g < 4; ++g)
          *(bf16x8*)&Al[tid * ASTR + g * 8] = *(bf16x8*)&a32[g * 8];
      }
      {
        const int dp = tid >> 3, mkg = (tid & 7) * 4;
        __bf16 u4[3][4];
#pragma unroll
        for (int j = 0; j < 4; ++j) {
          const int m = m0 + mkg + j;
          const bool bit = (vs_[m] >> dp) & 1u;
#pragma unroll
          for (int s = 0; s < 3; ++s)
            u4[s][j] = bit ? psp[s][m] : (__bf16)0.f;
        }
#pragma unroll
        for (int s = 0; s < 3; ++s)
          *(bf16x4v*)&Ul[s][dp * ASTR + mkg] = *(bf16x4v*)u4[s];
      }
      __syncthreads();
      bf16x8 bfr[3][2];
#pragma unroll
      for (int s = 0; s < 3; ++s)
#pragma unroll
        for (int nt = 0; nt < 2; ++nt)
          bfr[s][nt] = *(const bf16x8*)&Ul[s][(nt * 16 + nl) * ASTR + quad * 8];
#pragma unroll
      for (int mi = 0; mi < 4; ++mi) {
        const int mt2 = wid + mi * 4;
        if (mt2 < 13) {
          const bf16x8 af = *(const bf16x8*)&Al[(mt2 * 16 + nl) * ASTR + quad * 8];
#pragma unroll
          for (int nt = 0; nt < 2; ++nt) {
            f32x4 c = acc[mi][nt];
            c = __builtin_amdgcn_mfma_f32_16x16x32_bf16(af, bfr[0][nt], c, 0, 0, 0);
            c = __builtin_amdgcn_mfma_f32_16x16x32_bf16(af, bfr[1][nt], c, 0, 0, 0);
            c = __builtin_amdgcn_mfma_f32_16x16x32_bf16(af, bfr[2][nt], c, 0, 0, 0);
            acc[mi][nt] = c;
          }
        }
      }
      __syncthreads();
    }
    // epilogue: diag + *0.25, fused LIF(0.5), bf16 spike store
#pragma unroll
    for (int mi = 0; mi < 4; ++mi) {
      const int mt2 = wid + mi * 4;
      if (mt2 >= 13) continue;
#pragma unroll
      for (int r = 0; r < 4; ++r) {
        const int n = mt2 * 16 + quad * 4 + r;
        if (n >= Nn) continue;
        const float ann = (float)__popc(qs[n] & ks[n]);
        const float wd = ann * (1.0f - ps[n]);
        const u32 vn = vs_[n];
        __bf16* op = sp + (size_t)t * BCNn + ((size_t)bN * Nn + n) * Cn + h * 32;
#pragma unroll
        for (int nt = 0; nt < 2; ++nt) {
          const int d = nt * 16 + nl;
          const float bit = (float)((vn >> d) & 1u);
          const float y = (acc[mi][nt][r] + wd * bit) * 0.25f;
          const float vv = vst[mi][nt][r];
          const float nv = vv + (y - vv) * 0.5f;
          const bool s = nv >= 0.5f;
          vst[mi][nt][r] = s ? 0.f : nv;
          op[d] = (__bf16)(s ? 1.0f : 0.0f);
        }
      }
    }
  }
}

// ---------------------------------------------------------------------------
// proj GEMM: 3-split iv-scaled bf16 W x binary bf16 spikes (exact).
// ---------------------------------------------------------------------------
__global__ __launch_bounds__(256, 3) void gemm_proj_mfma(
    const __bf16* __restrict__ sp, const __bf16* __restrict__ wspb,
    const float* __restrict__ shv, float* __restrict__ z)
{
  __shared__ __bf16 Asw[3][128][32];
  __shared__ __bf16 Bsw[128][32];
  const int bid = blockIdx.x;
  const int xcd = bid & 7, slot = bid >> 3;      // slot 0..74
  const int gl = slot / 3, mt = slot - gl * 3;
  const int group = xcd * 25 + gl;
  if (group >= 196) return;
  const int colt = group % 49, t = group / 49;
  const int col0 = colt * 128, o0 = mt * 128;
  const int tid = threadIdx.x, lane = tid & 63, wid = tid >> 6;
  const int wm = wid >> 1, wn = wid & 1;
  const int quad = lane >> 4, nl = lane & 15;
  const __bf16* Bg = sp + ((size_t)t * NCOLS + col0) * Cn;

  f32x4 acc[4][4] = {};
  bf16x8 aval[6], bval[2];
#pragma unroll
  for (int i = 0; i < 6; ++i) {
    const int u = tid + i * 256, s = u >> 9, rem = u & 511;
    const int row = rem >> 2, kb = rem & 3;
    aval[i] = *(const bf16x8*)(wspb + (size_t)s * WSZ + (size_t)(o0 + row) * Cn + kb * 8);
  }
#pragma unroll
  for (int i = 0; i < 2; ++i) {
    const int u = tid + i * 256, row = u >> 2, kb = u & 3;
    bval[i] = *(const bf16x8*)(Bg + (size_t)row * Cn + kb * 8);
  }

  for (int kk = 0; kk < 12; ++kk) {
    __syncthreads();
#pragma unroll
    for (int i = 0; i < 6; ++i) {
      const int u = tid + i * 256, s = u >> 9, rem = u & 511;
      const int row = rem >> 2, kb = rem & 3;
      const int kbp = kb ^ ((row >> 1) & 3);
      *(bf16x8*)&Asw[s][row][kbp * 8] = aval[i];
    }
#pragma unroll
    for (int i = 0; i < 2; ++i) {
      const int u = tid + i * 256, row = u >> 2, kb = u & 3;
      const int kbp = kb ^ ((row >> 1) & 3);
      *(bf16x8*)&Bsw[row][kbp * 8] = bval[i];
    }
    __syncthreads();
    if (kk < 11) {
      const int k0n = (kk + 1) * 32;
#pragma unroll
      for (int i = 0; i < 6; ++i) {
        const int u = tid + i * 256, s = u >> 9, rem = u & 511;
        const int row = rem >> 2, kb = rem & 3;
        aval[i] = *(const bf16x8*)(wspb + (size_t)s * WSZ +
                                   (size_t)(o0 + row) * Cn + k0n + kb * 8);
      }
#pragma unroll
      for (int i = 0; i < 2; ++i) {
        const int u = tid + i * 256, row = u >> 2, kb = u & 3;
        bval[i] = *(const bf16x8*)(Bg + (size_t)row * Cn + k0n + kb * 8);
      }
    }
    bf16x8 af[3][4], bfr[4];
#pragma unroll
    for (int i = 0; i < 4; ++i) {
      const int ra = wm * 64 + i * 16 + nl;
      const int rb = wn * 64 + i * 16 + nl;
      const int ka = (quad ^ ((ra >> 1) & 3)) * 8;
      const int kb2 = (quad ^ ((rb >> 1) & 3)) * 8;
      bfr[i] = *(const bf16x8*)&Bsw[rb][kb2];
#pragma unroll
      for (int s = 0; s < 3; ++s)
        af[s][i] = *(const bf16x8*)&Asw[s][ra][ka];
    }
#pragma unroll
    for (int mi = 0; mi < 4; ++mi)
#pragma unroll
      for (int ni = 0; ni < 4; ++ni) {
        f32x4 c = acc[mi][ni];
        c = __builtin_amdgcn_mfma_f32_16x16x32_bf16(af[0][mi], bfr[ni], c, 0, 0, 0);
        c = __builtin_amdgcn_mfma_f32_16x16x32_bf16(af[1][mi], bfr[ni], c, 0, 0, 0);
        c = __builtin_amdgcn_mfma_f32_16x16x32_bf16(af[2][mi], bfr[ni], c, 0, 0, 0);
        acc[mi][ni] = c;
      }
  }
#pragma unroll
  for (int mi = 0; mi < 4; ++mi) {
    const int ob = o0 + wm * 64 + mi * 16 + quad * 4;
    const f32x4 sh4 = *(const f32x4*)&shv[3 * Cn + ob];
#pragma unroll
    for (int ni = 0; ni < 4; ++ni) {
      const int col = col0 + wn * 64 + ni * 16 + nl;
      const int b = col / Nn, nn = col - b * Nn;
      float* zp = z + (size_t)t * BCNn + (size_t)b * CNn + nn;
#pragma unroll
      for (int r = 0; r < 4; ++r)
        zp[(size_t)(ob + r) * Nn] = acc[mi][ni][r] + sh4[r];
    }
  }
}

// final LIF(1.0): z [t,b,o,n] fp32 -> out binary fp32
__global__ __launch_bounds__(256) void lif_out_v4(
    const float* __restrict__ z, float* __restrict__ out) {
  const size_t i4 = ((size_t)blockIdx.x * 256 + threadIdx.x) * 4;
  f32x4 v = {0.f, 0.f, 0.f, 0.f};
#pragma unroll
  for (int t = 0; t < Tn; ++t) {
    f32x4 x = *(const f32x4*)(z + (size_t)t * BCNn + i4);
    f32x4 o4;
#pragma unroll
    for (int r = 0; r < 4; ++r) {
      const float nv = v[r] + (x[r] - v[r]) * 0.5f;
      const bool s = nv >= 1.0f;
      o4[r] = s ? 1.0f : 0.0f;
      v[r] = s ? 0.f : nv;
    }
    *(f32x4*)(out + (size_t)t * BCNn + i4) = o4;
  }
}

// ===========================================================================
extern "C" void kernel_launch(void* const* d_in, const int* in_sizes, int n_in,
                              void* d_out, int out_size, void* d_ws, size_t ws_size,
                              hipStream_t stream) {
  const float* x      = (const float*)d_in[0];
  const float* policy = (const float*)d_in[1];
  const float* qw = (const float*)d_in[2];
  const float* qg = (const float*)d_in[3];
  const float* qb_ = (const float*)d_in[4];
  const float* qm = (const float*)d_in[5];
  const float* qv = (const float*)d_in[6];
  const float* kw = (const float*)d_in[7];
  const float* kg = (const float*)d_in[8];
  const float* kbe = (const float*)d_in[9];
  const float* km = (const float*)d_in[10];
  const float* kv = (const float*)d_in[11];
  const float* vw = (const float*)d_in[12];
  const float* vg = (const float*)d_in[13];
  const float* vbe = (const float*)d_in[14];
  const float* vm = (const float*)d_in[15];
  const float* vv = (const float*)d_in[16];
  const float* pw = (const float*)d_in[17];
  const float* pg = (const float*)d_in[18];
  const float* pbe = (const float*)d_in[19];
  const float* pm = (const float*)d_in[20];
  const float* pv = (const float*)d_in[21];
  const float* pbias = (const float*)d_in[22];
  float* out = (float*)d_out;

  char* base = (char*)d_ws;
  _Float16* xs   = (_Float16*)base;                               // 38,535,168
  _Float16* wsp16 = (_Float16*)(base + (size_t)TBCNn * 4);        //  1,769,472
  __bf16* wspb   = (__bf16*)((char*)wsp16 + (size_t)6 * WSZ * 2); //    884,736
  float* shv     = (float*)((char*)wspb + (size_t)3 * WSZ * 2);   //      6,144
  u32* bq        = (u32*)((char*)shv + 4 * Cn * 4);               //  1,204,224 x3
  u32* bk = bq + PBITS;
  u32* bv = bk + PBITS;
  __bf16* sp     = (__bf16*)(bv + PBITS);                         // 19,267,584
  float* z       = (float*)((char*)sp + (size_t)TBCNn * 2);       // 38,535,168

  WSplitArgs wa;
  wa.w[0] = qw; wa.g[0] = qg; wa.be[0] = qb_; wa.mu[0] = qm; wa.va[0] = qv;
  wa.w[1] = kw; wa.g[1] = kg; wa.be[1] = kbe; wa.mu[1] = km; wa.va[1] = kv;
  wa.w[2] = vw; wa.g[2] = vg; wa.be[2] = vbe; wa.mu[2] = vm; wa.va[2] = vv;
  wa.w[3] = pw; wa.g[3] = pg; wa.be[3] = pbe; wa.mu[3] = pm; wa.va[3] = pv;
  wa.bias = pbias;
  split_w<<<2304, 256, 0, stream>>>(wa, wsp16, wspb, shv);
  transpose_split_x<<<dim3(4, 32, 12), 256, 0, stream>>>(x, xs);

  gemm_qkv_lif<<<882, 256, 0, stream>>>(xs, wsp16, shv, bq, bk, bv);
  attn_lif<<<Bn * Hn, 256, 0, stream>>>(bq, bk, bv, policy, sp);
  gemm_proj_mfma<<<600, 256, 0, stream>>>(sp, wspb, shv, z);
  lif_out_v4<<<BCNn / 1024, 256, 0, stream>>>(z, out);
}

// Round 5
// 307.632 us; speedup vs baseline: 1.1864x; 1.0326x over previous
//
#include <hip/hip_runtime.h>

typedef unsigned int u32;
typedef __bf16 bf16x8 __attribute__((ext_vector_type(8)));
typedef __bf16 bf16x4v __attribute__((ext_vector_type(4)));
typedef _Float16 f16x8 __attribute__((ext_vector_type(8)));
typedef float f32x4 __attribute__((ext_vector_type(4)));

#define Tn 4
#define Bn 32
#define Cn 384
#define Nn 196
#define Hn 12
#define CNn (Cn*Nn)         // 75264
#define BCNn (Bn*CNn)       // 2408448
#define BHNn (Bn*Hn*Nn)     // 75264
#define PBITS (Tn*BHNn)     // 301056
#define TBCNn (Tn*BCNn)     // 9633792
#define NCOLS 6272          // B*N
#define WSZ 147456          // 384*384

// fp32 -> 3-way bf16 split (residual ~2^-24 rel)
__device__ __forceinline__ void split3(float v, __bf16& h, __bf16& m, __bf16& l) {
  h = (__bf16)v;  float r = v - (float)h;
  m = (__bf16)r;  float r2 = r - (float)m;
  l = (__bf16)r2;
}
// fp32 -> 2-way f16 split (residual ~2^-22 rel)
__device__ __forceinline__ void split2h(float v, _Float16& h, _Float16& l) {
  h = (_Float16)v;  l = (_Float16)(v - (float)h);
}

// direct global->LDS 16B copy: lane i lands at ldsbase + i*16 (wave-uniform base)
__device__ __forceinline__ void gl_lds16(const void* g, void* l) {
  __builtin_amdgcn_global_load_lds(
      (const __attribute__((address_space(1))) unsigned int*)g,
      (__attribute__((address_space(3))) unsigned int*)l, 16, 0, 0);
}

// ---------------------------------------------------------------------------
// W split: QKV (p<3) -> iv-scaled f16 2-split; proj -> iv-scaled bf16 3-split.
// ---------------------------------------------------------------------------
struct WSplitArgs {
  const float* w[4]; const float* g[4]; const float* be[4];
  const float* mu[4]; const float* va[4]; const float* bias;
};
__global__ __launch_bounds__(256) void split_w(
    WSplitArgs a, _Float16* __restrict__ wsp16, __bf16* __restrict__ wspb,
    float* __restrict__ shv) {
  const int i = blockIdx.x * 256 + threadIdx.x;   // < 589824
  const int p = i / WSZ, r = i - p * WSZ;
  const int o = r / Cn;
  const float iv = a.g[p][o] / sqrtf(a.va[p][o] + 1e-5f);
  const float wv = a.w[p][r] * iv;
  if (p < 3) {
    _Float16 h, l;
    split2h(wv, h, l);
    wsp16[(size_t)(p * 2 + 0) * WSZ + r] = h;
    wsp16[(size_t)(p * 2 + 1) * WSZ + r] = l;
  } else {
    __bf16 h, m, l;
    split3(wv, h, m, l);
    wspb[(size_t)0 * WSZ + r] = h;
    wspb[(size_t)1 * WSZ + r] = m;
    wspb[(size_t)2 * WSZ + r] = l;
  }
  if (r - o * Cn == 0) {
    float sh = a.be[p][o] - a.mu[p][o] * iv;
    if (p == 3) sh += a.bias[o] * iv;
    shv[p * Cn + o] = sh;
  }
}

// ---------------------------------------------------------------------------
// x [t,b,c,n] -> pre-split f16 planes xs[s][t][col=(b,n)][c], s=h/l.
// ---------------------------------------------------------------------------
__global__ __launch_bounds__(256) void transpose_split_x(
    const float* __restrict__ x, _Float16* __restrict__ xs) {
  __shared__ float tile[49 * 130];
  const int t = blockIdx.x, b = blockIdx.y;
  const int ct = blockIdx.z >> 2, nch = blockIdx.z & 3;
  const int c0 = ct * 128, n0 = nch * 49;
  const int tid = threadIdx.x;
  for (int idx = tid; idx < 49 * 128; idx += 256) {
    const int n = idx % 49, c = idx / 49;
    tile[n * 130 + c] = x[(size_t)t * BCNn + (size_t)b * CNn +
                          (size_t)(c0 + c) * Nn + n0 + n];
  }
  __syncthreads();
  for (int idx = tid; idx < 49 * 64; idx += 256) {
    const int cp = idx & 63, n = idx >> 6;
    const float v0 = tile[n * 130 + cp * 2];
    const float v1 = tile[n * 130 + cp * 2 + 1];
    _Float16 h0, l0, h1, l1;
    split2h(v0, h0, l0);
    split2h(v1, h1, l1);
    const size_t col = (size_t)t * NCOLS + (size_t)b * Nn + n0 + n;
    union { _Float16 f[2]; u32 u; } uh, ul;
    uh.f[0] = h0; uh.f[1] = h1;
    ul.f[0] = l0; ul.f[1] = l1;
    ((u32*)(xs + col * Cn + c0))[cp] = uh.u;
    ((u32*)(xs + (size_t)TBCNn + col * Cn + c0))[cp] = ul.u;
  }
}

// ---------------------------------------------------------------------------
// FUSED QKV GEMM + LIF(1.0) + bitpack, v4: t-pair interleave + A-frag reg
// reuse. Steps g=0..47 = (pair, kk, ti): A (weights) is t-invariant, so its
// LDS fragments are read ONCE per kk (even sub-step) and held in registers
// for the odd sub-step -> LDS read traffic -33%, A staging -50%. Ring
// buffers A x3 (48KB) + B x3 (24KB) = 72KB; counted uniform vmcnt(6) (B
// issued 2 sub-steps ahead, A 3 ahead) so the queue never drains (T3+T4).
// ---------------------------------------------------------------------------
__global__ __launch_bounds__(256, 2) void gemm_qkv_lif(
    const _Float16* __restrict__ xs,    // [2][t][col][c] f16 pre-split
    const _Float16* __restrict__ wsp16, // [3][2][o][c] iv-scaled f16 2-split
    const float* __restrict__ shv,      // [4][o]
    u32* __restrict__ bq, u32* __restrict__ bk, u32* __restrict__ bv)
{
  __shared__ _Float16 Asw[3][2][128][32];   // A ring: slot ai%3, 16KB each
  __shared__ _Float16 Bsw[3][2][64][32];    // B ring: slot g%3,   8KB each
  // bijective chunked XCD swizzle over 882 wgs (q=110, r=2): a colt's 9
  // (p,mt) variants stay consecutive on one XCD -> B-panel L2 reuse.
  const int orig = blockIdx.x;
  const int xcd = orig & 7, i8 = orig >> 3;
  const int wgid = xcd * 110 + (xcd < 2 ? xcd : 2) + i8;
  const int colt = wgid / 9, v = wgid - colt * 9;
  const int col0 = colt * 64;
  const int p = v / 3, mt = v - p * 3;
  const int o0 = mt * 128;
  const int tid = threadIdx.x, lane = tid & 63, wid = tid >> 6;
  const int wm = wid >> 1, wn = wid & 1;
  const int quad = lane >> 4, nl = lane & 15;
  u32* __restrict__ bits = (p == 0) ? bq : (p == 1) ? bk : bv;

  // per-lane staging source offsets (pre-swizzled so linear LDS dest +
  // XOR-swizzled fragment reads are conflict-free; rule #21).
  u32 aOff[4], bOff[2];
#pragma unroll
  for (int i = 0; i < 4; ++i) {
    const int c = i * 256 + wid * 64 + lane;     // A chunk 0..1023
    const int s = c >> 9, row = (c >> 2) & 127, kb = c & 3;
    const int kbs = kb ^ ((row >> 1) & 3);
    aOff[i] = (u32)((((p * 2 + s) * WSZ) + (o0 + row) * Cn + kbs * 8) * 2);
  }
#pragma unroll
  for (int i = 0; i < 2; ++i) {
    const int c = i * 256 + wid * 64 + lane;     // B chunk 0..511
    const int s = c >> 8, rem = c & 255, row = rem >> 2, kb = rem & 3;
    const int kbs = kb ^ ((row >> 1) & 3);
    bOff[i] = (u32)(((size_t)s * TBCNn + (size_t)(col0 + row) * Cn + kbs * 8) * 2);
  }
  const char* wB = (const char*)wsp16;
  const char* xB = (const char*)xs;
  char* aD0 = (char*)&Asw[0][0][0][0] + wid * 1024;
  char* bD0 = (char*)&Bsw[0][0][0][0] + wid * 1024;

  // A-tile for sequential index ai (kk = ai%12) into ring slot ai%3
#define STAGE_A(ai_) do {                                                  \
    const u32 ak_ = (u32)(((ai_) % 12) * 64);                              \
    char* d_ = aD0 + ((ai_) % 3) * 16384;                                  \
    _Pragma("unroll") for (int i_ = 0; i_ < 4; ++i_)                       \
      gl_lds16(wB + aOff[i_] + ak_, d_ + i_ * 4096);                       \
  } while (0)
  // B-tile for step g (t = (g/24)*2 + (g&1), kk = (g%24)>>1) into slot g%3
#define STAGE_B(g_) do {                                                   \
    const int t_ = ((g_) / 24) * 2 + ((g_) & 1);                           \
    const int kk_ = (((g_) % 24) >> 1);                                    \
    const u32 bk_ = (u32)(kk_ * 64) + (u32)t_ * (u32)(NCOLS * Cn * 2);     \
    char* d_ = bD0 + ((g_) % 3) * 8192;                                    \
    _Pragma("unroll") for (int i_ = 0; i_ < 2; ++i_)                       \
      gl_lds16(xB + bOff[i_] + bk_, d_ + i_ * 4096);                       \
  } while (0)

  // BN shift, t-invariant
  f32x4 sh_[4];
#pragma unroll
  for (int mi = 0; mi < 4; ++mi)
    sh_[mi] = *(const f32x4*)&shv[p * Cn + o0 + wm * 64 + mi * 16 + quad * 4];

  f32x4 acc0[4][2], acc1[4][2];   // ti=0 / ti=1 accumulators
  f32x4 vst[4][2] = {};           // LIF membrane, persists across t

  // epilogue: LIF + bitpack for one t (register-only + global bit store)
  auto epi = [&](f32x4 (&ac)[4][2], int t) {
#pragma unroll
    for (int ni = 0; ni < 2; ++ni) {
      u32 w0 = 0, w1 = 0;
#pragma unroll
      for (int mi = 0; mi < 4; ++mi) {
#pragma unroll
        for (int r = 0; r < 4; ++r) {
          const float y = ac[mi][ni][r] + sh_[mi][r];
          const float vv = vst[mi][ni][r];
          const float nv = vv + (y - vv) * 0.5f;
          const bool sk = nv >= 1.0f;
          vst[mi][ni][r] = sk ? 0.f : nv;
          const u32 b1 = sk ? 1u : 0u;
          const int pos = ((mi & 1) << 4) + (quad << 2) + r;
          if (mi < 2) w0 |= b1 << pos; else w1 |= b1 << pos;
        }
      }
      // OR across the 4 quads (lanes nl, nl+16, nl+32, nl+48)
      w0 |= __shfl_xor(w0, 16); w0 |= __shfl_xor(w0, 32);
      w1 |= __shfl_xor(w1, 16); w1 |= __shfl_xor(w1, 32);
      if (quad == 0) {
        const int col = col0 + wn * 32 + ni * 16 + nl;
        const int bb = col / Nn, nn = col - bb * Nn;
        u32* bp = bits + (size_t)t * BHNn +
                  ((size_t)bb * Hn + (mt * 4 + wm * 2)) * Nn + nn;
        bp[0] = w0;       // h = mt*4 + wm*2
        bp[Nn] = w1;      // h = mt*4 + wm*2 + 1
      }
    }
  };

  // prologue (FIFO order matters for the vmcnt counting): B0, A0, B1, A1
  STAGE_B(0); STAGE_A(0); STAGE_B(1); STAGE_A(1);

#pragma unroll 1
  for (int gg = 0; gg < 24; ++gg) {
    const int abuf = gg % 3;
    const int be = (2 * gg) % 3, bo = (2 * gg + 1) % 3;
    const int kk = gg % 12;

    // ===== even sub-step: g = 2gg, ti = 0 =====
    if (gg < 23) { asm volatile("s_waitcnt vmcnt(6)" ::: "memory"); }
    else         { asm volatile("s_waitcnt vmcnt(2)" ::: "memory"); }
    __builtin_amdgcn_s_barrier();
    __builtin_amdgcn_sched_barrier(0);
    if (gg < 23) STAGE_B(2 * gg + 2);
    if (kk == 0) {
#pragma unroll
      for (int mi = 0; mi < 4; ++mi)
#pragma unroll
        for (int ni = 0; ni < 2; ++ni) {
          acc0[mi][ni] = f32x4{0.f, 0.f, 0.f, 0.f};
          acc1[mi][ni] = f32x4{0.f, 0.f, 0.f, 0.f};
        }
    }
    // A fragments: read once, reused by the odd sub-step (t-invariant)
    f16x8 af0[4], af1[4];
#pragma unroll
    for (int mi = 0; mi < 4; ++mi) {
      const int ra = wm * 64 + mi * 16 + nl;
      const int ka = (quad ^ ((ra >> 1) & 3)) * 8;
      af0[mi] = *(const f16x8*)&Asw[abuf][0][ra][ka];
      af1[mi] = *(const f16x8*)&Asw[abuf][1][ra][ka];
    }
    {
      f16x8 bfr[2][2];
#pragma unroll
      for (int i = 0; i < 2; ++i) {
        const int rb = wn * 32 + i * 16 + nl;
        const int kb2 = (quad ^ ((rb >> 1) & 3)) * 8;
        bfr[0][i] = *(const f16x8*)&Bsw[be][0][rb][kb2];
        bfr[1][i] = *(const f16x8*)&Bsw[be][1][rb][kb2];
      }
      __builtin_amdgcn_s_setprio(1);
#pragma unroll
      for (int mi = 0; mi < 4; ++mi)
#pragma unroll
        for (int ni = 0; ni < 2; ++ni) {
          f32x4 c = acc0[mi][ni];
          c = __builtin_amdgcn_mfma_f32_16x16x32_f16(af0[mi], bfr[0][ni], c, 0, 0, 0);
          c = __builtin_amdgcn_mfma_f32_16x16x32_f16(af0[mi], bfr[1][ni], c, 0, 0, 0);
          c = __builtin_amdgcn_mfma_f32_16x16x32_f16(af1[mi], bfr[0][ni], c, 0, 0, 0);
          acc0[mi][ni] = c;
        }
      __builtin_amdgcn_s_setprio(0);
    }

    // ===== odd sub-step: g = 2gg+1, ti = 1 (reuses af0/af1) =====
    if (gg < 23) { asm volatile("s_waitcnt vmcnt(6)" ::: "memory"); }
    else         { asm volatile("s_waitcnt vmcnt(0)" ::: "memory"); }
    __builtin_amdgcn_s_barrier();
    __builtin_amdgcn_sched_barrier(0);
    if (gg < 23) STAGE_B(2 * gg + 3);
    if (gg < 22) STAGE_A(gg + 2);
    {
      f16x8 bfr[2][2];
#pragma unroll
      for (int i = 0; i < 2; ++i) {
        const int rb = wn * 32 + i * 16 + nl;
        const int kb2 = (quad ^ ((rb >> 1) & 3)) * 8;
        bfr[0][i] = *(const f16x8*)&Bsw[bo][0][rb][kb2];
        bfr[1][i] = *(const f16x8*)&Bsw[bo][1][rb][kb2];
      }
      __builtin_amdgcn_s_setprio(1);
#pragma unroll
      for (int mi = 0; mi < 4; ++mi)
#pragma unroll
        for (int ni = 0; ni < 2; ++ni) {
          f32x4 c = acc1[mi][ni];
          c = __builtin_amdgcn_mfma_f32_16x16x32_f16(af0[mi], bfr[0][ni], c, 0, 0, 0);
          c = __builtin_amdgcn_mfma_f32_16x16x32_f16(af0[mi], bfr[1][ni], c, 0, 0, 0);
          c = __builtin_amdgcn_mfma_f32_16x16x32_f16(af1[mi], bfr[0][ni], c, 0, 0, 0);
          acc1[mi][ni] = c;
        }
      __builtin_amdgcn_s_setprio(0);
    }
    if (kk == 11) {
      const int p2 = gg / 12;
      epi(acc0, p2 * 2 + 0);
      epi(acc1, p2 * 2 + 1);
    }
  }
#undef STAGE_A
#undef STAGE_B
}

// ---------------------------------------------------------------------------
// FUSED MFMA attention + LIF(0.5). One block per (b,h) = 384 blocks; t-loop
// inside so LIF state stays in registers; emits bf16 spikes directly to sp.
// y = A.U + diag, A[n,m]=popc(q&k) (exact bf16 int), U[m,d]=p_m*v[m,d]
// (exact fp32, 3-split bf16), diag adds a(n,n)*(1-p_n)*v[n,d].
// ---------------------------------------------------------------------------
#define ASTR 40
__global__ __launch_bounds__(256) void attn_lif(
    const u32* __restrict__ qb, const u32* __restrict__ kb,
    const u32* __restrict__ vb, const float* __restrict__ policy,
    __bf16* __restrict__ sp) {
  __shared__ u32 qs[208], ks[224], vs_[224];
  __shared__ float ps[224];
  __shared__ __bf16 psp[3][224];
  __shared__ __bf16 Al[208 * ASTR];
  __shared__ __bf16 Ul[3][32 * ASTR];
  const int bh = blockIdx.x;           // b*H + h
  const int bN = bh / Hn;
  const int h = bh - bN * Hn;
  const int tid = threadIdx.x;
  const int lane = tid & 63, wid = tid >> 6;
  const int quad = lane >> 4, nl = lane & 15;

  float vst[4][2][4] = {};   // LIF(0.5) membrane, persistent across t

  for (int t = 0; t < Tn; ++t) {
    const int tb = t * Bn + bN;
    const int gid = tb * Hn + h;
    if (t) __syncthreads();   // prior epilogue reads qs/vs_/ps done
    // stage bits + policy (zero-padded)
    for (int i = tid; i < 224; i += 256) {
      const bool in = i < Nn;
      if (i < 208) qs[i] = in ? qb[(size_t)gid * Nn + i] : 0u;
      ks[i] = in ? kb[(size_t)gid * Nn + i] : 0u;
      vs_[i] = in ? vb[(size_t)gid * Nn + i] : 0u;
      const float p = in ? policy[(size_t)tb * Nn + i] : 0.f;
      ps[i] = p;
      __bf16 hh, mm, ll;
      split3(p, hh, mm, ll);
      psp[0][i] = hh; psp[1][i] = mm; psp[2][i] = ll;
    }
    __syncthreads();

    f32x4 acc[4][2] = {};

    for (int slab = 0; slab < 7; ++slab) {
      const int m0 = slab * 32;
      if (tid < 208) {
        const u32 qn = qs[tid];
        __bf16 a32[32];
#pragma unroll
        for (int mk = 0; mk < 32; ++mk)
          a32[mk] = (__bf16)(float)__popc(qn & ks[m0 + mk]);
#pragma unroll
        for (int g = 0; g < 4; ++g)
          *(bf16x8*)&Al[tid * ASTR + g * 8] = *(bf16x8*)&a32[g * 8];
      }
      {
        const int dp = tid >> 3, mkg = (tid & 7) * 4;
        __bf16 u4[3][4];
#pragma unroll
        for (int j = 0; j < 4; ++j) {
          const int m = m0 + mkg + j;
          const bool bit = (vs_[m] >> dp) & 1u;
#pragma unroll
          for (int s = 0; s < 3; ++s)
            u4[s][j] = bit ? psp[s][m] : (__bf16)0.f;
        }
#pragma unroll
        for (int s = 0; s < 3; ++s)
          *(bf16x4v*)&Ul[s][dp * ASTR + mkg] = *(bf16x4v*)u4[s];
      }
      __syncthreads();
      bf16x8 bfr[3][2];
#pragma unroll
      for (int s = 0; s < 3; ++s)
#pragma unroll
        for (int nt = 0; nt < 2; ++nt)
          bfr[s][nt] = *(const bf16x8*)&Ul[s][(nt * 16 + nl) * ASTR + quad * 8];
#pragma unroll
      for (int mi = 0; mi < 4; ++mi) {
        const int mt2 = wid + mi * 4;
        if (mt2 < 13) {
          const bf16x8 af = *(const bf16x8*)&Al[(mt2 * 16 + nl) * ASTR + quad * 8];
#pragma unroll
          for (int nt = 0; nt < 2; ++nt) {
            f32x4 c = acc[mi][nt];
            c = __builtin_amdgcn_mfma_f32_16x16x32_bf16(af, bfr[0][nt], c, 0, 0, 0);
            c = __builtin_amdgcn_mfma_f32_16x16x32_bf16(af, bfr[1][nt], c, 0, 0, 0);
            c = __builtin_amdgcn_mfma_f32_16x16x32_bf16(af, bfr[2][nt], c, 0, 0, 0);
            acc[mi][nt] = c;
          }
        }
      }
      __syncthreads();
    }
    // epilogue: diag + *0.25, fused LIF(0.5), bf16 spike store
#pragma unroll
    for (int mi = 0; mi < 4; ++mi) {
      const int mt2 = wid + mi * 4;
      if (mt2 >= 13) continue;
#pragma unroll
      for (int r = 0; r < 4; ++r) {
        const int n = mt2 * 16 + quad * 4 + r;
        if (n >= Nn) continue;
        const float ann = (float)__popc(qs[n] & ks[n]);
        const float wd = ann * (1.0f - ps[n]);
        const u32 vn = vs_[n];
        __bf16* op = sp + (size_t)t * BCNn + ((size_t)bN * Nn + n) * Cn + h * 32;
#pragma unroll
        for (int nt = 0; nt < 2; ++nt) {
          const int d = nt * 16 + nl;
          const float bit = (float)((vn >> d) & 1u);
          const float y = (acc[mi][nt][r] + wd * bit) * 0.25f;
          const float vv = vst[mi][nt][r];
          const float nv = vv + (y - vv) * 0.5f;
          const bool s = nv >= 0.5f;
          vst[mi][nt][r] = s ? 0.f : nv;
          op[d] = (__bf16)(s ? 1.0f : 0.0f);
        }
      }
    }
  }
}

// ---------------------------------------------------------------------------
// proj GEMM: 3-split iv-scaled bf16 W x binary bf16 spikes (exact).
// ---------------------------------------------------------------------------
__global__ __launch_bounds__(256, 3) void gemm_proj_mfma(
    const __bf16* __restrict__ sp, const __bf16* __restrict__ wspb,
    const float* __restrict__ shv, float* __restrict__ z)
{
  __shared__ __bf16 Asw[3][128][32];
  __shared__ __bf16 Bsw[128][32];
  const int bid = blockIdx.x;
  const int xcd = bid & 7, slot = bid >> 3;      // slot 0..74
  const int gl = slot / 3, mt = slot - gl * 3;
  const int group = xcd * 25 + gl;
  if (group >= 196) return;
  const int colt = group % 49, t = group / 49;
  const int col0 = colt * 128, o0 = mt * 128;
  const int tid = threadIdx.x, lane = tid & 63, wid = tid >> 6;
  const int wm = wid >> 1, wn = wid & 1;
  const int quad = lane >> 4, nl = lane & 15;
  const __bf16* Bg = sp + ((size_t)t * NCOLS + col0) * Cn;

  f32x4 acc[4][4] = {};
  bf16x8 aval[6], bval[2];
#pragma unroll
  for (int i = 0; i < 6; ++i) {
    const int u = tid + i * 256, s = u >> 9, rem = u & 511;
    const int row = rem >> 2, kb = rem & 3;
    aval[i] = *(const bf16x8*)(wspb + (size_t)s * WSZ + (size_t)(o0 + row) * Cn + kb * 8);
  }
#pragma unroll
  for (int i = 0; i < 2; ++i) {
    const int u = tid + i * 256, row = u >> 2, kb = u & 3;
    bval[i] = *(const bf16x8*)(Bg + (size_t)row * Cn + kb * 8);
  }

  for (int kk = 0; kk < 12; ++kk) {
    __syncthreads();
#pragma unroll
    for (int i = 0; i < 6; ++i) {
      const int u = tid + i * 256, s = u >> 9, rem = u & 511;
      const int row = rem >> 2, kb = rem & 3;
      const int kbp = kb ^ ((row >> 1) & 3);
      *(bf16x8*)&Asw[s][row][kbp * 8] = aval[i];
    }
#pragma unroll
    for (int i = 0; i < 2; ++i) {
      const int u = tid + i * 256, row = u >> 2, kb = u & 3;
      const int kbp = kb ^ ((row >> 1) & 3);
      *(bf16x8*)&Bsw[row][kbp * 8] = bval[i];
    }
    __syncthreads();
    if (kk < 11) {
      const int k0n = (kk + 1) * 32;
#pragma unroll
      for (int i = 0; i < 6; ++i) {
        const int u = tid + i * 256, s = u >> 9, rem = u & 511;
        const int row = rem >> 2, kb = rem & 3;
        aval[i] = *(const bf16x8*)(wspb + (size_t)s * WSZ +
                                   (size_t)(o0 + row) * Cn + k0n + kb * 8);
      }
#pragma unroll
      for (int i = 0; i < 2; ++i) {
        const int u = tid + i * 256, row = u >> 2, kb = u & 3;
        bval[i] = *(const bf16x8*)(Bg + (size_t)row * Cn + k0n + kb * 8);
      }
    }
    bf16x8 af[3][4], bfr[4];
#pragma unroll
    for (int i = 0; i < 4; ++i) {
      const int ra = wm * 64 + i * 16 + nl;
      const int rb = wn * 64 + i * 16 + nl;
      const int ka = (quad ^ ((ra >> 1) & 3)) * 8;
      const int kb2 = (quad ^ ((rb >> 1) & 3)) * 8;
      bfr[i] = *(const bf16x8*)&Bsw[rb][kb2];
#pragma unroll
      for (int s = 0; s < 3; ++s)
        af[s][i] = *(const bf16x8*)&Asw[s][ra][ka];
    }
#pragma unroll
    for (int mi = 0; mi < 4; ++mi)
#pragma unroll
      for (int ni = 0; ni < 4; ++ni) {
        f32x4 c = acc[mi][ni];
        c = __builtin_amdgcn_mfma_f32_16x16x32_bf16(af[0][mi], bfr[ni], c, 0, 0, 0);
        c = __builtin_amdgcn_mfma_f32_16x16x32_bf16(af[1][mi], bfr[ni], c, 0, 0, 0);
        c = __builtin_amdgcn_mfma_f32_16x16x32_bf16(af[2][mi], bfr[ni], c, 0, 0, 0);
        acc[mi][ni] = c;
      }
  }
#pragma unroll
  for (int mi = 0; mi < 4; ++mi) {
    const int ob = o0 + wm * 64 + mi * 16 + quad * 4;
    const f32x4 sh4 = *(const f32x4*)&shv[3 * Cn + ob];
#pragma unroll
    for (int ni = 0; ni < 4; ++ni) {
      const int col = col0 + wn * 64 + ni * 16 + nl;
      const int b = col / Nn, nn = col - b * Nn;
      float* zp = z + (size_t)t * BCNn + (size_t)b * CNn + nn;
#pragma unroll
      for (int r = 0; r < 4; ++r)
        zp[(size_t)(ob + r) * Nn] = acc[mi][ni][r] + sh4[r];
    }
  }
}

// final LIF(1.0): z [t,b,o,n] fp32 -> out binary fp32
__global__ __launch_bounds__(256) void lif_out_v4(
    const float* __restrict__ z, float* __restrict__ out) {
  const size_t i4 = ((size_t)blockIdx.x * 256 + threadIdx.x) * 4;
  f32x4 v = {0.f, 0.f, 0.f, 0.f};
#pragma unroll
  for (int t = 0; t < Tn; ++t) {
    f32x4 x = *(const f32x4*)(z + (size_t)t * BCNn + i4);
    f32x4 o4;
#pragma unroll
    for (int r = 0; r < 4; ++r) {
      const float nv = v[r] + (x[r] - v[r]) * 0.5f;
      const bool s = nv >= 1.0f;
      o4[r] = s ? 1.0f : 0.0f;
      v[r] = s ? 0.f : nv;
    }
    *(f32x4*)(out + (size_t)t * BCNn + i4) = o4;
  }
}

// ===========================================================================
extern "C" void kernel_launch(void* const* d_in, const int* in_sizes, int n_in,
                              void* d_out, int out_size, void* d_ws, size_t ws_size,
                              hipStream_t stream) {
  const float* x      = (const float*)d_in[0];
  const float* policy = (const float*)d_in[1];
  const float* qw = (const float*)d_in[2];
  const float* qg = (const float*)d_in[3];
  const float* qb_ = (const float*)d_in[4];
  const float* qm = (const float*)d_in[5];
  const float* qv = (const float*)d_in[6];
  const float* kw = (const float*)d_in[7];
  const float* kg = (const float*)d_in[8];
  const float* kbe = (const float*)d_in[9];
  const float* km = (const float*)d_in[10];
  const float* kv = (const float*)d_in[11];
  const float* vw = (const float*)d_in[12];
  const float* vg = (const float*)d_in[13];
  const float* vbe = (const float*)d_in[14];
  const float* vm = (const float*)d_in[15];
  const float* vv = (const float*)d_in[16];
  const float* pw = (const float*)d_in[17];
  const float* pg = (const float*)d_in[18];
  const float* pbe = (const float*)d_in[19];
  const float* pm = (const float*)d_in[20];
  const float* pv = (const float*)d_in[21];
  const float* pbias = (const float*)d_in[22];
  float* out = (float*)d_out;

  char* base = (char*)d_ws;
  _Float16* xs   = (_Float16*)base;                               // 38,535,168
  _Float16* wsp16 = (_Float16*)(base + (size_t)TBCNn * 4);        //  1,769,472
  __bf16* wspb   = (__bf16*)((char*)wsp16 + (size_t)6 * WSZ * 2); //    884,736
  float* shv     = (float*)((char*)wspb + (size_t)3 * WSZ * 2);   //      6,144
  u32* bq        = (u32*)((char*)shv + 4 * Cn * 4);               //  1,204,224 x3
  u32* bk = bq + PBITS;
  u32* bv = bk + PBITS;
  __bf16* sp     = (__bf16*)(bv + PBITS);                         // 19,267,584
  float* z       = (float*)((char*)sp + (size_t)TBCNn * 2);       // 38,535,168

  WSplitArgs wa;
  wa.w[0] = qw; wa.g[0] = qg; wa.be[0] = qb_; wa.mu[0] = qm; wa.va[0] = qv;
  wa.w[1] = kw; wa.g[1] = kg; wa.be[1] = kbe; wa.mu[1] = km; wa.va[1] = kv;
  wa.w[2] = vw; wa.g[2] = vg; wa.be[2] = vbe; wa.mu[2] = vm; wa.va[2] = vv;
  wa.w[3] = pw; wa.g[3] = pg; wa.be[3] = pbe; wa.mu[3] = pm; wa.va[3] = pv;
  wa.bias = pbias;
  split_w<<<2304, 256, 0, stream>>>(wa, wsp16, wspb, shv);
  transpose_split_x<<<dim3(4, 32, 12), 256, 0, stream>>>(x, xs);

  gemm_qkv_lif<<<882, 256, 0, stream>>>(xs, wsp16, shv, bq, bk, bv);
  attn_lif<<<Bn * Hn, 256, 0, stream>>>(bq, bk, bv, policy, sp);
  gemm_proj_mfma<<<600, 256, 0, stream>>>(sp, wspb, shv, z);
  lif_out_v4<<<BCNn / 1024, 256, 0, stream>>>(z, out);
}

// Round 6
// 296.949 us; speedup vs baseline: 1.2290x; 1.0360x over previous
//
#include <hip/hip_runtime.h>

typedef unsigned int u32;
typedef __bf16 bf16x8 __attribute__((ext_vector_type(8)));
typedef __bf16 bf16x4v __attribute__((ext_vector_type(4)));
typedef _Float16 f16x8 __attribute__((ext_vector_type(8)));
typedef float f32x4 __attribute__((ext_vector_type(4)));

#define Tn 4
#define Bn 32
#define Cn 384
#define Nn 196
#define Hn 12
#define CNn (Cn*Nn)         // 75264
#define BCNn (Bn*CNn)       // 2408448
#define BHNn (Bn*Hn*Nn)     // 75264
#define PBITS (Tn*BHNn)     // 301056
#define TBCNn (Tn*BCNn)     // 9633792
#define NCOLS 6272          // B*N
#define WSZ 147456          // 384*384

// fp32 -> 3-way bf16 split (residual ~2^-24 rel)
__device__ __forceinline__ void split3(float v, __bf16& h, __bf16& m, __bf16& l) {
  h = (__bf16)v;  float r = v - (float)h;
  m = (__bf16)r;  float r2 = r - (float)m;
  l = (__bf16)r2;
}
// fp32 -> 2-way f16 split (residual ~2^-22 rel)
__device__ __forceinline__ void split2h(float v, _Float16& h, _Float16& l) {
  h = (_Float16)v;  l = (_Float16)(v - (float)h);
}

// direct global->LDS 16B copy: lane i lands at ldsbase + i*16 (wave-uniform base)
__device__ __forceinline__ void gl_lds16(const void* g, void* l) {
  __builtin_amdgcn_global_load_lds(
      (const __attribute__((address_space(1))) unsigned int*)g,
      (__attribute__((address_space(3))) unsigned int*)l, 16, 0, 0);
}

// ---------------------------------------------------------------------------
// MERGED prep: blocks [0,2304) = W split; [2304,3840) = x transpose+split.
// Independent work, one launch (saves a dispatch ramp + tail).
// ---------------------------------------------------------------------------
struct WSplitArgs {
  const float* w[4]; const float* g[4]; const float* be[4];
  const float* mu[4]; const float* va[4]; const float* bias;
};
__global__ __launch_bounds__(256) void prep(
    WSplitArgs a, _Float16* __restrict__ wsp16, __bf16* __restrict__ wspb,
    float* __restrict__ shv, const float* __restrict__ x,
    _Float16* __restrict__ xs) {
  __shared__ float tile[49 * 130];
  const int bx = blockIdx.x;
  const int tid = threadIdx.x;
  if (bx < 2304) {
    // ---- split_w ----
    const int i = bx * 256 + tid;                 // < 589824
    const int p = i / WSZ, r = i - p * WSZ;
    const int o = r / Cn;
    const float iv = a.g[p][o] / sqrtf(a.va[p][o] + 1e-5f);
    const float wv = a.w[p][r] * iv;
    if (p < 3) {
      _Float16 h, l;
      split2h(wv, h, l);
      wsp16[(size_t)(p * 2 + 0) * WSZ + r] = h;
      wsp16[(size_t)(p * 2 + 1) * WSZ + r] = l;
    } else {
      __bf16 h, m, l;
      split3(wv, h, m, l);
      wspb[(size_t)0 * WSZ + r] = h;
      wspb[(size_t)1 * WSZ + r] = m;
      wspb[(size_t)2 * WSZ + r] = l;
    }
    if (r - o * Cn == 0) {
      float sh = a.be[p][o] - a.mu[p][o] * iv;
      if (p == 3) sh += a.bias[o] * iv;
      shv[p * Cn + o] = sh;
    }
    return;
  }
  // ---- transpose_split_x ----
  const int bid2 = bx - 2304;                     // < 1536
  const int t = bid2 & 3, b = (bid2 >> 2) & 31, zz = bid2 >> 7;
  const int ct = zz >> 2, nch = zz & 3;
  const int c0 = ct * 128, n0 = nch * 49;
  for (int idx = tid; idx < 49 * 128; idx += 256) {
    const int n = idx % 49, c = idx / 49;
    tile[n * 130 + c] = x[(size_t)t * BCNn + (size_t)b * CNn +
                          (size_t)(c0 + c) * Nn + n0 + n];
  }
  __syncthreads();
  for (int idx = tid; idx < 49 * 64; idx += 256) {
    const int cp = idx & 63, n = idx >> 6;
    const float v0 = tile[n * 130 + cp * 2];
    const float v1 = tile[n * 130 + cp * 2 + 1];
    _Float16 h0, l0, h1, l1;
    split2h(v0, h0, l0);
    split2h(v1, h1, l1);
    const size_t col = (size_t)t * NCOLS + (size_t)b * Nn + n0 + n;
    union { _Float16 f[2]; u32 u; } uh, ul;
    uh.f[0] = h0; uh.f[1] = h1;
    ul.f[0] = l0; ul.f[1] = l1;
    ((u32*)(xs + col * Cn + c0))[cp] = uh.u;
    ((u32*)(xs + (size_t)TBCNn + col * Cn + c0))[cp] = ul.u;
  }
}

// ---------------------------------------------------------------------------
// FUSED QKV GEMM + LIF(1.0) + bitpack (UNCHANGED from R5: validated 89us).
// ---------------------------------------------------------------------------
__global__ __launch_bounds__(256, 2) void gemm_qkv_lif(
    const _Float16* __restrict__ xs,    // [2][t][col][c] f16 pre-split
    const _Float16* __restrict__ wsp16, // [3][2][o][c] iv-scaled f16 2-split
    const float* __restrict__ shv,      // [4][o]
    u32* __restrict__ bq, u32* __restrict__ bk, u32* __restrict__ bv)
{
  __shared__ _Float16 Asw[3][2][128][32];   // A ring: slot ai%3, 16KB each
  __shared__ _Float16 Bsw[3][2][64][32];    // B ring: slot g%3,   8KB each
  const int orig = blockIdx.x;
  const int xcd = orig & 7, i8 = orig >> 3;
  const int wgid = xcd * 110 + (xcd < 2 ? xcd : 2) + i8;
  const int colt = wgid / 9, v = wgid - colt * 9;
  const int col0 = colt * 64;
  const int p = v / 3, mt = v - p * 3;
  const int o0 = mt * 128;
  const int tid = threadIdx.x, lane = tid & 63, wid = tid >> 6;
  const int wm = wid >> 1, wn = wid & 1;
  const int quad = lane >> 4, nl = lane & 15;
  u32* __restrict__ bits = (p == 0) ? bq : (p == 1) ? bk : bv;

  u32 aOff[4], bOff[2];
#pragma unroll
  for (int i = 0; i < 4; ++i) {
    const int c = i * 256 + wid * 64 + lane;     // A chunk 0..1023
    const int s = c >> 9, row = (c >> 2) & 127, kb = c & 3;
    const int kbs = kb ^ ((row >> 1) & 3);
    aOff[i] = (u32)((((p * 2 + s) * WSZ) + (o0 + row) * Cn + kbs * 8) * 2);
  }
#pragma unroll
  for (int i = 0; i < 2; ++i) {
    const int c = i * 256 + wid * 64 + lane;     // B chunk 0..511
    const int s = c >> 8, rem = c & 255, row = rem >> 2, kb = rem & 3;
    const int kbs = kb ^ ((row >> 1) & 3);
    bOff[i] = (u32)(((size_t)s * TBCNn + (size_t)(col0 + row) * Cn + kbs * 8) * 2);
  }
  const char* wB = (const char*)wsp16;
  const char* xB = (const char*)xs;
  char* aD0 = (char*)&Asw[0][0][0][0] + wid * 1024;
  char* bD0 = (char*)&Bsw[0][0][0][0] + wid * 1024;

#define STAGE_A(ai_) do {                                                  \
    const u32 ak_ = (u32)(((ai_) % 12) * 64);                              \
    char* d_ = aD0 + ((ai_) % 3) * 16384;                                  \
    _Pragma("unroll") for (int i_ = 0; i_ < 4; ++i_)                       \
      gl_lds16(wB + aOff[i_] + ak_, d_ + i_ * 4096);                       \
  } while (0)
#define STAGE_B(g_) do {                                                   \
    const int t_ = ((g_) / 24) * 2 + ((g_) & 1);                           \
    const int kk_ = (((g_) % 24) >> 1);                                    \
    const u32 bk_ = (u32)(kk_ * 64) + (u32)t_ * (u32)(NCOLS * Cn * 2);     \
    char* d_ = bD0 + ((g_) % 3) * 8192;                                    \
    _Pragma("unroll") for (int i_ = 0; i_ < 2; ++i_)                       \
      gl_lds16(xB + bOff[i_] + bk_, d_ + i_ * 4096);                       \
  } while (0)

  f32x4 sh_[4];
#pragma unroll
  for (int mi = 0; mi < 4; ++mi)
    sh_[mi] = *(const f32x4*)&shv[p * Cn + o0 + wm * 64 + mi * 16 + quad * 4];

  f32x4 acc0[4][2], acc1[4][2];
  f32x4 vst[4][2] = {};

  auto epi = [&](f32x4 (&ac)[4][2], int t) {
#pragma unroll
    for (int ni = 0; ni < 2; ++ni) {
      u32 w0 = 0, w1 = 0;
#pragma unroll
      for (int mi = 0; mi < 4; ++mi) {
#pragma unroll
        for (int r = 0; r < 4; ++r) {
          const float y = ac[mi][ni][r] + sh_[mi][r];
          const float vv = vst[mi][ni][r];
          const float nv = vv + (y - vv) * 0.5f;
          const bool sk = nv >= 1.0f;
          vst[mi][ni][r] = sk ? 0.f : nv;
          const u32 b1 = sk ? 1u : 0u;
          const int pos = ((mi & 1) << 4) + (quad << 2) + r;
          if (mi < 2) w0 |= b1 << pos; else w1 |= b1 << pos;
        }
      }
      w0 |= __shfl_xor(w0, 16); w0 |= __shfl_xor(w0, 32);
      w1 |= __shfl_xor(w1, 16); w1 |= __shfl_xor(w1, 32);
      if (quad == 0) {
        const int col = col0 + wn * 32 + ni * 16 + nl;
        const int bb = col / Nn, nn = col - bb * Nn;
        u32* bp = bits + (size_t)t * BHNn +
                  ((size_t)bb * Hn + (mt * 4 + wm * 2)) * Nn + nn;
        bp[0] = w0;
        bp[Nn] = w1;
      }
    }
  };

  STAGE_B(0); STAGE_A(0); STAGE_B(1); STAGE_A(1);

#pragma unroll 1
  for (int gg = 0; gg < 24; ++gg) {
    const int abuf = gg % 3;
    const int be = (2 * gg) % 3, bo = (2 * gg + 1) % 3;
    const int kk = gg % 12;

    if (gg < 23) { asm volatile("s_waitcnt vmcnt(6)" ::: "memory"); }
    else         { asm volatile("s_waitcnt vmcnt(2)" ::: "memory"); }
    __builtin_amdgcn_s_barrier();
    __builtin_amdgcn_sched_barrier(0);
    if (gg < 23) STAGE_B(2 * gg + 2);
    if (kk == 0) {
#pragma unroll
      for (int mi = 0; mi < 4; ++mi)
#pragma unroll
        for (int ni = 0; ni < 2; ++ni) {
          acc0[mi][ni] = f32x4{0.f, 0.f, 0.f, 0.f};
          acc1[mi][ni] = f32x4{0.f, 0.f, 0.f, 0.f};
        }
    }
    f16x8 af0[4], af1[4];
#pragma unroll
    for (int mi = 0; mi < 4; ++mi) {
      const int ra = wm * 64 + mi * 16 + nl;
      const int ka = (quad ^ ((ra >> 1) & 3)) * 8;
      af0[mi] = *(const f16x8*)&Asw[abuf][0][ra][ka];
      af1[mi] = *(const f16x8*)&Asw[abuf][1][ra][ka];
    }
    {
      f16x8 bfr[2][2];
#pragma unroll
      for (int i = 0; i < 2; ++i) {
        const int rb = wn * 32 + i * 16 + nl;
        const int kb2 = (quad ^ ((rb >> 1) & 3)) * 8;
        bfr[0][i] = *(const f16x8*)&Bsw[be][0][rb][kb2];
        bfr[1][i] = *(const f16x8*)&Bsw[be][1][rb][kb2];
      }
      __builtin_amdgcn_s_setprio(1);
#pragma unroll
      for (int mi = 0; mi < 4; ++mi)
#pragma unroll
        for (int ni = 0; ni < 2; ++ni) {
          f32x4 c = acc0[mi][ni];
          c = __builtin_amdgcn_mfma_f32_16x16x32_f16(af0[mi], bfr[0][ni], c, 0, 0, 0);
          c = __builtin_amdgcn_mfma_f32_16x16x32_f16(af0[mi], bfr[1][ni], c, 0, 0, 0);
          c = __builtin_amdgcn_mfma_f32_16x16x32_f16(af1[mi], bfr[0][ni], c, 0, 0, 0);
          acc0[mi][ni] = c;
        }
      __builtin_amdgcn_s_setprio(0);
    }

    if (gg < 23) { asm volatile("s_waitcnt vmcnt(6)" ::: "memory"); }
    else         { asm volatile("s_waitcnt vmcnt(0)" ::: "memory"); }
    __builtin_amdgcn_s_barrier();
    __builtin_amdgcn_sched_barrier(0);
    if (gg < 23) STAGE_B(2 * gg + 3);
    if (gg < 22) STAGE_A(gg + 2);
    {
      f16x8 bfr[2][2];
#pragma unroll
      for (int i = 0; i < 2; ++i) {
        const int rb = wn * 32 + i * 16 + nl;
        const int kb2 = (quad ^ ((rb >> 1) & 3)) * 8;
        bfr[0][i] = *(const f16x8*)&Bsw[bo][0][rb][kb2];
        bfr[1][i] = *(const f16x8*)&Bsw[bo][1][rb][kb2];
      }
      __builtin_amdgcn_s_setprio(1);
#pragma unroll
      for (int mi = 0; mi < 4; ++mi)
#pragma unroll
        for (int ni = 0; ni < 2; ++ni) {
          f32x4 c = acc1[mi][ni];
          c = __builtin_amdgcn_mfma_f32_16x16x32_f16(af0[mi], bfr[0][ni], c, 0, 0, 0);
          c = __builtin_amdgcn_mfma_f32_16x16x32_f16(af0[mi], bfr[1][ni], c, 0, 0, 0);
          c = __builtin_amdgcn_mfma_f32_16x16x32_f16(af1[mi], bfr[0][ni], c, 0, 0, 0);
          acc1[mi][ni] = c;
        }
      __builtin_amdgcn_s_setprio(0);
    }
    if (kk == 11) {
      const int p2 = gg / 12;
      epi(acc0, p2 * 2 + 0);
      epi(acc1, p2 * 2 + 1);
    }
  }
#undef STAGE_A
#undef STAGE_B
}

// ---------------------------------------------------------------------------
// FUSED MFMA attention + LIF(0.5), M-SPLIT: block = ((b*H+h)*2 + half), 768
// blocks (was 384 @1.5/CU -> 3/CU). half0 owns M-tiles 0..6 (n 0..111),
// half1 owns 7..12 (n 112..207). Halves the serial A-build per block and
// doubles latency hiding. LIF rows disjoint across halves -> exact.
// ---------------------------------------------------------------------------
#define ASTR 40
__global__ __launch_bounds__(256) void attn_lif(
    const u32* __restrict__ qb, const u32* __restrict__ kb,
    const u32* __restrict__ vb, const float* __restrict__ policy,
    __bf16* __restrict__ sp) {
  __shared__ u32 qs[208], ks[224], vs_[224];
  __shared__ float ps[224];
  __shared__ __bf16 psp[3][224];
  __shared__ __bf16 Al[112 * ASTR];
  __shared__ __bf16 Ul[3][32 * ASTR];
  const int blk = blockIdx.x;          // (b*H + h)*2 + half
  const int half = blk & 1;
  const int bh = blk >> 1;
  const int bN = bh / Hn;
  const int h = bh - bN * Hn;
  const int nbase = half * 112;        // global n of local tile 0
  const int ntiles = half ? 6 : 7;
  const int nrows = ntiles * 16;       // 112 / 96
  const int tid = threadIdx.x;
  const int lane = tid & 63, wid = tid >> 6;
  const int quad = lane >> 4, nl = lane & 15;

  float vst[2][2][4] = {};   // LIF(0.5) membrane for own rows, across t

  for (int t = 0; t < Tn; ++t) {
    const int tb = t * Bn + bN;
    const int gid = tb * Hn + h;
    if (t) __syncthreads();   // prior epilogue reads qs/vs_/ps done
    // stage bits + policy (zero-padded); qs full (epilogue diag needs own n)
    for (int i = tid; i < 224; i += 256) {
      const bool in = i < Nn;
      if (i < 208) qs[i] = in ? qb[(size_t)gid * Nn + i] : 0u;
      ks[i] = in ? kb[(size_t)gid * Nn + i] : 0u;
      vs_[i] = in ? vb[(size_t)gid * Nn + i] : 0u;
      const float p = in ? policy[(size_t)tb * Nn + i] : 0.f;
      ps[i] = p;
      __bf16 hh, mm, ll;
      split3(p, hh, mm, ll);
      psp[0][i] = hh; psp[1][i] = mm; psp[2][i] = ll;
    }
    __syncthreads();

    f32x4 acc[2][2] = {};

    for (int slab = 0; slab < 7; ++slab) {
      const int m0 = slab * 32;
      // A-slab: only this half's rows
      if (tid < nrows) {
        const u32 qn = qs[nbase + tid];
        __bf16 a32[32];
#pragma unroll
        for (int mk = 0; mk < 32; ++mk)
          a32[mk] = (__bf16)(float)__popc(qn & ks[m0 + mk]);
#pragma unroll
        for (int g = 0; g < 4; ++g)
          *(bf16x8*)&Al[tid * ASTR + g * 8] = *(bf16x8*)&a32[g * 8];
      }
      {
        const int dp = tid >> 3, mkg = (tid & 7) * 4;
        __bf16 u4[3][4];
#pragma unroll
        for (int j = 0; j < 4; ++j) {
          const int m = m0 + mkg + j;
          const bool bit = (vs_[m] >> dp) & 1u;
#pragma unroll
          for (int s = 0; s < 3; ++s)
            u4[s][j] = bit ? psp[s][m] : (__bf16)0.f;
        }
#pragma unroll
        for (int s = 0; s < 3; ++s)
          *(bf16x4v*)&Ul[s][dp * ASTR + mkg] = *(bf16x4v*)u4[s];
      }
      __syncthreads();
      bf16x8 bfr[3][2];
#pragma unroll
      for (int s = 0; s < 3; ++s)
#pragma unroll
        for (int nt = 0; nt < 2; ++nt)
          bfr[s][nt] = *(const bf16x8*)&Ul[s][(nt * 16 + nl) * ASTR + quad * 8];
#pragma unroll
      for (int mi = 0; mi < 2; ++mi) {
        const int lt = wid + mi * 4;
        if (lt < ntiles) {
          const bf16x8 af = *(const bf16x8*)&Al[(lt * 16 + nl) * ASTR + quad * 8];
#pragma unroll
          for (int nt = 0; nt < 2; ++nt) {
            f32x4 c = acc[mi][nt];
            c = __builtin_amdgcn_mfma_f32_16x16x32_bf16(af, bfr[0][nt], c, 0, 0, 0);
            c = __builtin_amdgcn_mfma_f32_16x16x32_bf16(af, bfr[1][nt], c, 0, 0, 0);
            c = __builtin_amdgcn_mfma_f32_16x16x32_bf16(af, bfr[2][nt], c, 0, 0, 0);
            acc[mi][nt] = c;
          }
        }
      }
      __syncthreads();
    }
    // epilogue: diag + *0.25, fused LIF(0.5), bf16 spike store
#pragma unroll
    for (int mi = 0; mi < 2; ++mi) {
      const int lt = wid + mi * 4;
      if (lt >= ntiles) continue;
#pragma unroll
      for (int r = 0; r < 4; ++r) {
        const int n = nbase + lt * 16 + quad * 4 + r;
        if (n >= Nn) continue;
        const float ann = (float)__popc(qs[n] & ks[n]);
        const float wd = ann * (1.0f - ps[n]);
        const u32 vn = vs_[n];
        __bf16* op = sp + (size_t)t * BCNn + ((size_t)bN * Nn + n) * Cn + h * 32;
#pragma unroll
        for (int nt = 0; nt < 2; ++nt) {
          const int d = nt * 16 + nl;
          const float bit = (float)((vn >> d) & 1u);
          const float y = (acc[mi][nt][r] + wd * bit) * 0.25f;
          const float vv = vst[mi][nt][r];
          const float nv = vv + (y - vv) * 0.5f;
          const bool s = nv >= 0.5f;
          vst[mi][nt][r] = s ? 0.f : nv;
          op[d] = (__bf16)(s ? 1.0f : 0.0f);
        }
      }
    }
  }
}

// ---------------------------------------------------------------------------
// proj GEMM v2: global_load_lds staging (R1-proven pattern; was reg-staged =
// Common-mistake #1). Pre-swizzled per-lane sources, linear LDS dest, same
// XOR fragment reads -> bit-identical MFMA inputs.
// ---------------------------------------------------------------------------
__global__ __launch_bounds__(256, 3) void gemm_proj_mfma(
    const __bf16* __restrict__ sp, const __bf16* __restrict__ wspb,
    const float* __restrict__ shv, float* __restrict__ z)
{
  __shared__ __bf16 Asw[3][128][32];
  __shared__ __bf16 Bsw[128][32];
  const int bid = blockIdx.x;
  const int xcd = bid & 7, slot = bid >> 3;      // slot 0..74
  const int gl = slot / 3, mt = slot - gl * 3;
  const int group = xcd * 25 + gl;
  if (group >= 196) return;
  const int colt = group % 49, t = group / 49;
  const int col0 = colt * 128, o0 = mt * 128;
  const int tid = threadIdx.x, lane = tid & 63, wid = tid >> 6;
  const int wm = wid >> 1, wn = wid & 1;
  const int quad = lane >> 4, nl = lane & 15;
  const __bf16* Bg = sp + ((size_t)t * NCOLS + col0) * Cn;

  // per-lane staging source addresses (pre-swizzled, rule #21)
  const char* aSrc[6];
  const char* bSrc[2];
#pragma unroll
  for (int i = 0; i < 6; ++i) {
    const int c = i * 256 + wid * 64 + lane;     // A chunk 0..1535
    const int s = c >> 9, rem = c & 511;
    const int row = rem >> 2, kb = rem & 3;
    const int kbs = kb ^ ((row >> 1) & 3);
    aSrc[i] = (const char*)(wspb + (size_t)s * WSZ +
                            (size_t)(o0 + row) * Cn + kbs * 8);
  }
#pragma unroll
  for (int i = 0; i < 2; ++i) {
    const int c = i * 256 + wid * 64 + lane;     // B chunk 0..511
    const int row = c >> 2, kb = c & 3;
    const int kbs = kb ^ ((row >> 1) & 3);
    bSrc[i] = (const char*)(Bg + (size_t)row * Cn + kbs * 8);
  }
  char* aDst = (char*)&Asw[0][0][0] + wid * 1024;
  char* bDst = (char*)&Bsw[0][0] + wid * 1024;

  f32x4 acc[4][4] = {};

  for (int kk = 0; kk < 12; ++kk) {
    const int koff = kk * 64;   // 32 bf16 = 64 bytes per K-step
#pragma unroll
    for (int i = 0; i < 6; ++i) gl_lds16(aSrc[i] + koff, aDst + i * 4096);
#pragma unroll
    for (int i = 0; i < 2; ++i) gl_lds16(bSrc[i] + koff, bDst + i * 4096);
    __syncthreads();
    bf16x8 af[3][4], bfr[4];
#pragma unroll
    for (int i = 0; i < 4; ++i) {
      const int ra = wm * 64 + i * 16 + nl;
      const int rb = wn * 64 + i * 16 + nl;
      const int ka = (quad ^ ((ra >> 1) & 3)) * 8;
      const int kb2 = (quad ^ ((rb >> 1) & 3)) * 8;
      bfr[i] = *(const bf16x8*)&Bsw[rb][kb2];
#pragma unroll
      for (int s = 0; s < 3; ++s)
        af[s][i] = *(const bf16x8*)&Asw[s][ra][ka];
    }
#pragma unroll
    for (int mi = 0; mi < 4; ++mi)
#pragma unroll
      for (int ni = 0; ni < 4; ++ni) {
        f32x4 c = acc[mi][ni];
        c = __builtin_amdgcn_mfma_f32_16x16x32_bf16(af[0][mi], bfr[ni], c, 0, 0, 0);
        c = __builtin_amdgcn_mfma_f32_16x16x32_bf16(af[1][mi], bfr[ni], c, 0, 0, 0);
        c = __builtin_amdgcn_mfma_f32_16x16x32_bf16(af[2][mi], bfr[ni], c, 0, 0, 0);
        acc[mi][ni] = c;
      }
    __syncthreads();
  }
#pragma unroll
  for (int mi = 0; mi < 4; ++mi) {
    const int ob = o0 + wm * 64 + mi * 16 + quad * 4;
    const f32x4 sh4 = *(const f32x4*)&shv[3 * Cn + ob];
#pragma unroll
    for (int ni = 0; ni < 4; ++ni) {
      const int col = col0 + wn * 64 + ni * 16 + nl;
      const int b = col / Nn, nn = col - b * Nn;
      float* zp = z + (size_t)t * BCNn + (size_t)b * CNn + nn;
#pragma unroll
      for (int r = 0; r < 4; ++r)
        zp[(size_t)(ob + r) * Nn] = acc[mi][ni][r] + sh4[r];
    }
  }
}

// final LIF(1.0): z [t,b,o,n] fp32 -> out binary fp32
__global__ __launch_bounds__(256) void lif_out_v4(
    const float* __restrict__ z, float* __restrict__ out) {
  const size_t i4 = ((size_t)blockIdx.x * 256 + threadIdx.x) * 4;
  f32x4 v = {0.f, 0.f, 0.f, 0.f};
#pragma unroll
  for (int t = 0; t < Tn; ++t) {
    f32x4 x = *(const f32x4*)(z + (size_t)t * BCNn + i4);
    f32x4 o4;
#pragma unroll
    for (int r = 0; r < 4; ++r) {
      const float nv = v[r] + (x[r] - v[r]) * 0.5f;
      const bool s = nv >= 1.0f;
      o4[r] = s ? 1.0f : 0.0f;
      v[r] = s ? 0.f : nv;
    }
    *(f32x4*)(out + (size_t)t * BCNn + i4) = o4;
  }
}

// ===========================================================================
extern "C" void kernel_launch(void* const* d_in, const int* in_sizes, int n_in,
                              void* d_out, int out_size, void* d_ws, size_t ws_size,
                              hipStream_t stream) {
  const float* x      = (const float*)d_in[0];
  const float* policy = (const float*)d_in[1];
  const float* qw = (const float*)d_in[2];
  const float* qg = (const float*)d_in[3];
  const float* qb_ = (const float*)d_in[4];
  const float* qm = (const float*)d_in[5];
  const float* qv = (const float*)d_in[6];
  const float* kw = (const float*)d_in[7];
  const float* kg = (const float*)d_in[8];
  const float* kbe = (const float*)d_in[9];
  const float* km = (const float*)d_in[10];
  const float* kv = (const float*)d_in[11];
  const float* vw = (const float*)d_in[12];
  const float* vg = (const float*)d_in[13];
  const float* vbe = (const float*)d_in[14];
  const float* vm = (const float*)d_in[15];
  const float* vv = (const float*)d_in[16];
  const float* pw = (const float*)d_in[17];
  const float* pg = (const float*)d_in[18];
  const float* pbe = (const float*)d_in[19];
  const float* pm = (const float*)d_in[20];
  const float* pv = (const float*)d_in[21];
  const float* pbias = (const float*)d_in[22];
  float* out = (float*)d_out;

  char* base = (char*)d_ws;
  _Float16* xs   = (_Float16*)base;                               // 38,535,168
  _Float16* wsp16 = (_Float16*)(base + (size_t)TBCNn * 4);        //  1,769,472
  __bf16* wspb   = (__bf16*)((char*)wsp16 + (size_t)6 * WSZ * 2); //    884,736
  float* shv     = (float*)((char*)wspb + (size_t)3 * WSZ * 2);   //      6,144
  u32* bq        = (u32*)((char*)shv + 4 * Cn * 4);               //  1,204,224 x3
  u32* bk = bq + PBITS;
  u32* bv = bk + PBITS;
  __bf16* sp     = (__bf16*)(bv + PBITS);                         // 19,267,584
  float* z       = (float*)((char*)sp + (size_t)TBCNn * 2);       // 38,535,168

  WSplitArgs wa;
  wa.w[0] = qw; wa.g[0] = qg; wa.be[0] = qb_; wa.mu[0] = qm; wa.va[0] = qv;
  wa.w[1] = kw; wa.g[1] = kg; wa.be[1] = kbe; wa.mu[1] = km; wa.va[1] = kv;
  wa.w[2] = vw; wa.g[2] = vg; wa.be[2] = vbe; wa.mu[2] = vm; wa.va[2] = vv;
  wa.w[3] = pw; wa.g[3] = pg; wa.be[3] = pbe; wa.mu[3] = pm; wa.va[3] = pv;
  wa.bias = pbias;
  prep<<<3840, 256, 0, stream>>>(wa, wsp16, wspb, shv, x, xs);

  gemm_qkv_lif<<<882, 256, 0, stream>>>(xs, wsp16, shv, bq, bk, bv);
  attn_lif<<<2 * Bn * Hn, 256, 0, stream>>>(bq, bk, bv, policy, sp);
  gemm_proj_mfma<<<600, 256, 0, stream>>>(sp, wspb, shv, z);
  lif_out_v4<<<BCNn / 1024, 256, 0, stream>>>(z, out);
}